// Round 2
// baseline (132.397 us; speedup 1.0000x reference)
//
#include <hip/hip_runtime.h>
#include <hip/hip_bf16.h>
#include <math.h>

#define NH 8
#define C_ 512
#define C3 1536
#define NTOK 16384   // b*t*h*w = 2*8*32*32

typedef __attribute__((ext_vector_type(8))) short short8;
typedef __attribute__((ext_vector_type(4))) float f32x4;
typedef __attribute__((address_space(3))) void* lds_ptr_t;
typedef const __attribute__((address_space(1))) void* gbl_ptr_t;

static __device__ __forceinline__ ushort f2bf(float f) {
  __hip_bfloat16 h = __float2bfloat16(f);
  return *reinterpret_cast<ushort*>(&h);
}
static __device__ __forceinline__ float bf2f(ushort u) {
  uint t = ((uint)u) << 16;
  float f;
  __builtin_memcpy(&f, &t, 4);
  return f;
}

// ---------------------------------------------------------------------------
// K0: fused fp32 -> bf16 cast for x, w_in, w_out PLUS cos/sin table for rope.
// csn[idx] = (cosf(freqs[idx]), sinf(freqs[idx])), idx over 8*32*32*32 = 262144.
// ---------------------------------------------------------------------------
__global__ __launch_bounds__(256) void cast3_kernel(
    const float* __restrict__ x, const float* __restrict__ wi,
    const float* __restrict__ wo, const float* __restrict__ fr,
    ushort* __restrict__ xb, ushort* __restrict__ wib,
    ushort* __restrict__ wob, float2* __restrict__ csn) {
  const int blk = blockIdx.x;
  if (blk >= 4608) {   // 128 blocks: sincos table (8 entries/thread)
    int i = (blk - 4608) * 256 + threadIdx.x;
    const float4* fp = (const float4*)fr + (size_t)i * 2;
    float4 a = fp[0], b = fp[1];
    float v[8] = {a.x, a.y, a.z, a.w, b.x, b.y, b.z, b.w};
    float2 o[8];
#pragma unroll
    for (int j = 0; j < 8; ++j) { o[j].x = cosf(v[j]); o[j].y = sinf(v[j]); }
    float4* op = (float4*)(csn + (size_t)i * 8);
    op[0] = make_float4(o[0].x, o[0].y, o[1].x, o[1].y);
    op[1] = make_float4(o[2].x, o[2].y, o[3].x, o[3].y);
    op[2] = make_float4(o[4].x, o[4].y, o[5].x, o[5].y);
    op[3] = make_float4(o[6].x, o[6].y, o[7].x, o[7].y);
    return;
  }
  const float* src;
  ushort* dst;
  int i;
  if (blk < 4096)      { src = x;  dst = xb;  i = blk * 256 + threadIdx.x; }
  else if (blk < 4480) { src = wi; dst = wib; i = (blk - 4096) * 256 + threadIdx.x; }
  else                 { src = wo; dst = wob; i = (blk - 4480) * 256 + threadIdx.x; }
  const float4* p = (const float4*)src + (size_t)i * 2;
  float4 v0 = p[0], v1 = p[1];
  union { ushort u[8]; uint4 v; } r;
  r.u[0] = f2bf(v0.x); r.u[1] = f2bf(v0.y); r.u[2] = f2bf(v0.z); r.u[3] = f2bf(v0.w);
  r.u[4] = f2bf(v1.x); r.u[5] = f2bf(v1.y); r.u[6] = f2bf(v1.z); r.u[7] = f2bf(v1.w);
  *(uint4*)(dst + (size_t)i * 8) = r.v;
}

// ---------------------------------------------------------------------------
// Shared 128x128x32 GEMM main loop pieces (proven R8 structure):
// prefetch double-buffer, T2 source swizzle, T1 XCD swizzle.
// ---------------------------------------------------------------------------
#define TBM 128
#define TBN 128
#define TBK 32
#define TILE_U ((TBM + TBN) * TBK)

static __device__ __forceinline__ void stage_tile(
    const ushort* __restrict__ A, const ushort* __restrict__ B,
    ushort* As, ushort* Bs, int bm, int bn, int K, int k0, int tid) {
#pragma unroll
  for (int it = 0; it < 2; ++it) {
    int c = it * 256 + tid;
    int row = c >> 2;
    int sk = ((c & 3) ^ ((row >> 1) & 3)) * 8;
    __builtin_amdgcn_global_load_lds(
        (gbl_ptr_t)(const void*)(A + (size_t)(bm + row) * K + k0 + sk),
        (lds_ptr_t)(As + (size_t)c * 8), 16, 0, 0);
    __builtin_amdgcn_global_load_lds(
        (gbl_ptr_t)(const void*)(B + (size_t)(bn + row) * K + k0 + sk),
        (lds_ptr_t)(Bs + (size_t)c * 8), 16, 0, 0);
  }
}

// ---------------------------------------------------------------------------
// K1: qkv GEMM with FUSED RMSNorm + RoPE epilogue (bf16 out).
// Each 64-ch head chunk lies fully inside a 128-wide tile (bn, n*192+{0,64,128}
// all 64-aligned). Epilogue: stage half-tile (64 rows x 128 cols) in LDS
// (stride 136 for bank spread + 16B alignment), 2 threads per (row, 64-chunk),
// shfl-pair sum-of-squares, rsqrt, gamma, rope from precomputed cos/sin table.
// v chunks pass through (select, no divergence). Numerics identical to the
// old separate norm_rope kernel (same bf16 staging, same sinf/cosf).
// ---------------------------------------------------------------------------
#define CSTR 136

__global__ __launch_bounds__(256) void gemm_qkv_fused(
    const ushort* __restrict__ A, const ushort* __restrict__ B,
    ushort* __restrict__ C, int N, int K, int GX,
    const float2* __restrict__ csn, const float* __restrict__ qg,
    const float* __restrict__ kg) {
  __shared__ ushort smem[2 * TILE_U];
  __shared__ float gsh[128];
  const int tid  = threadIdx.x;
  const int wave = tid >> 6;
  const int lane = tid & 63;
  const int nwg = gridDim.x;
  const int wg = (blockIdx.x & 7) * (nwg >> 3) + (blockIdx.x >> 3);
  const int bm = (wg / GX) * TBM;
  const int bn = (wg % GX) * TBN;
  const int wr = (wave >> 1) * 64;
  const int wc = (wave & 1) * 64;
  const int lm = lane & 15;
  const int g4 = lane >> 4;

  if (tid < 128) gsh[tid] = (tid < 64) ? qg[tid] : kg[tid - 64];

  f32x4 acc[4][4];
#pragma unroll
  for (int m = 0; m < 4; ++m)
#pragma unroll
    for (int n = 0; n < 4; ++n) acc[m][n] = (f32x4){0.f, 0.f, 0.f, 0.f};

  const int ko = (g4 ^ ((lm >> 1) & 3)) * 8;

  const int nt = K / TBK;
  stage_tile(A, B, smem, smem + TBM * TBK, bm, bn, K, 0, tid);
  __syncthreads();

  int cur = 0;
  for (int t = 0; t < nt; ++t) {
    if (t + 1 < nt) {
      ushort* Asn = smem + (cur ^ 1) * TILE_U;
      stage_tile(A, B, Asn, Asn + TBM * TBK, bm, bn, K, (t + 1) * TBK, tid);
    }
    const ushort* As = smem + cur * TILE_U;
    const ushort* Bs = As + TBM * TBK;
    short8 av[4], bv[4];
#pragma unroll
    for (int m = 0; m < 4; ++m)
      av[m] = *(const short8*)&As[(wr + m * 16 + lm) * TBK + ko];
#pragma unroll
    for (int n = 0; n < 4; ++n)
      bv[n] = *(const short8*)&Bs[(wc + n * 16 + lm) * TBK + ko];
#pragma unroll
    for (int m = 0; m < 4; ++m)
#pragma unroll
      for (int n = 0; n < 4; ++n)
        acc[m][n] = __builtin_amdgcn_mfma_f32_16x16x32_bf16(av[m], bv[n], acc[m][n], 0, 0, 0);
    __syncthreads();
    cur ^= 1;
  }

  // ---- fused epilogue ----
  const int cr = g4 * 4;
  const int cc = lm;
  ushort* Cs = smem;
  const int row_e = tid >> 2;          // 0..63
  const int cg    = (tid >> 1) & 1;    // which 64-chunk of the 128 cols
  const int half  = tid & 1;           // which 32-half of the chunk
  const int colg  = bn + cg * 64;      // global col start of chunk
  const int type  = (colg % 192) >> 6; // 0=q, 1=k, 2=v
  const int gofs  = (type & 1) * 64;   // gamma base (q or k; v selected away)

#pragma unroll
  for (int h = 0; h < 2; ++h) {
    __syncthreads();
    if ((wave >> 1) == h) {
#pragma unroll
      for (int m = 0; m < 4; ++m)
#pragma unroll
        for (int n = 0; n < 4; ++n)
#pragma unroll
          for (int r = 0; r < 4; ++r)
            Cs[(m * 16 + cr + r) * CSTR + wc + n * 16 + cc] = f2bf(acc[m][n][r]);
    }
    __syncthreads();
    union { uint4 q[4]; ushort u[32]; } L;
    {
      const uint4* srcp = (const uint4*)&Cs[row_e * CSTR + cg * 64 + half * 32];
      L.q[0] = srcp[0]; L.q[1] = srcp[1]; L.q[2] = srcp[2]; L.q[3] = srcp[3];
    }
    const int tokm = bm + h * 64 + row_e;
    float f[32], ss = 0.f;
#pragma unroll
    for (int j = 0; j < 32; ++j) { f[j] = bf2f(L.u[j]); ss += f[j] * f[j]; }
    ss += __shfl_xor(ss, 1);
    const float rn = rsqrtf(ss * (1.f / 64.f) + 1e-6f);
    const int tloc = (tokm >> 10) & 7;
    const float2* cb = csn + (((size_t)((tloc << 10) | (tokm & 1023))) << 5) + half * 16;
    union { uint4 q[4]; ushort u[32]; } O;
#pragma unroll
    for (int dj = 0; dj < 16; ++dj) {
      float2 cs2 = cb[dj];
      float2 gg = *(const float2*)&gsh[gofs + (half * 16 + dj) * 2];
      float xe = f[2 * dj]     * rn * gg.x;
      float xo = f[2 * dj + 1] * rn * gg.y;
      O.u[2 * dj]     = f2bf(xe * cs2.x - xo * cs2.y);
      O.u[2 * dj + 1] = f2bf(xe * cs2.y + xo * cs2.x);
    }
    if (type == 2) { O.q[0] = L.q[0]; O.q[1] = L.q[1]; O.q[2] = L.q[2]; O.q[3] = L.q[3]; }
    uint4* dst = (uint4*)(C + (size_t)tokm * N + colg + half * 32);
    dst[0] = O.q[0]; dst[1] = O.q[1]; dst[2] = O.q[2]; dst[3] = O.q[3];
  }
}

// ---------------------------------------------------------------------------
// K1b: plain NT GEMM (fp32 out) for the output projection (unchanged).
// ---------------------------------------------------------------------------
template <bool BF16OUT>
__global__ __launch_bounds__(256) void gemm_bt_bf16(
    const ushort* __restrict__ A, const ushort* __restrict__ B,
    void* __restrict__ Cv, int N, int K, int GX) {
  __shared__ ushort smem[2 * TILE_U];
  const int tid  = threadIdx.x;
  const int wave = tid >> 6;
  const int lane = tid & 63;
  const int nwg = gridDim.x;
  const int wg = (blockIdx.x & 7) * (nwg >> 3) + (blockIdx.x >> 3);
  const int bm = (wg / GX) * TBM;
  const int bn = (wg % GX) * TBN;
  const int wr = (wave >> 1) * 64;
  const int wc = (wave & 1) * 64;
  const int lm = lane & 15;
  const int g4 = lane >> 4;

  f32x4 acc[4][4];
#pragma unroll
  for (int m = 0; m < 4; ++m)
#pragma unroll
    for (int n = 0; n < 4; ++n) acc[m][n] = (f32x4){0.f, 0.f, 0.f, 0.f};

  const int ko = (g4 ^ ((lm >> 1) & 3)) * 8;

  const int nt = K / TBK;
  stage_tile(A, B, smem, smem + TBM * TBK, bm, bn, K, 0, tid);
  __syncthreads();

  int cur = 0;
  for (int t = 0; t < nt; ++t) {
    if (t + 1 < nt) {
      ushort* Asn = smem + (cur ^ 1) * TILE_U;
      stage_tile(A, B, Asn, Asn + TBM * TBK, bm, bn, K, (t + 1) * TBK, tid);
    }
    const ushort* As = smem + cur * TILE_U;
    const ushort* Bs = As + TBM * TBK;
    short8 av[4], bv[4];
#pragma unroll
    for (int m = 0; m < 4; ++m)
      av[m] = *(const short8*)&As[(wr + m * 16 + lm) * TBK + ko];
#pragma unroll
    for (int n = 0; n < 4; ++n)
      bv[n] = *(const short8*)&Bs[(wc + n * 16 + lm) * TBK + ko];
#pragma unroll
    for (int m = 0; m < 4; ++m)
#pragma unroll
      for (int n = 0; n < 4; ++n)
        acc[m][n] = __builtin_amdgcn_mfma_f32_16x16x32_bf16(av[m], bv[n], acc[m][n], 0, 0, 0);
    __syncthreads();
    cur ^= 1;
  }

  const int cr = g4 * 4;
  const int cc = lm;

  if (BF16OUT) {
    ushort* Cs = smem;
    ushort* C = (ushort*)Cv;
#pragma unroll
    for (int h = 0; h < 2; ++h) {
      __syncthreads();
      if ((wave >> 1) == h) {
#pragma unroll
        for (int m = 0; m < 4; ++m)
#pragma unroll
          for (int n = 0; n < 4; ++n)
#pragma unroll
            for (int r = 0; r < 4; ++r)
              Cs[(m * 16 + cr + r) * 128 + wc + n * 16 + cc] = f2bf(acc[m][n][r]);
      }
      __syncthreads();
#pragma unroll
      for (int i = 0; i < 4; ++i) {
        int idx = i * 256 + tid;
        int row = idx >> 4, ch = idx & 15;
        uint4 v = *(const uint4*)&Cs[row * 128 + ch * 8];
        *(uint4*)(C + (size_t)(bm + h * 64 + row) * N + bn + ch * 8) = v;
      }
    }
  } else {
    float* Csf = (float*)smem;
    float* C = (float*)Cv;
#pragma unroll
    for (int s = 0; s < 4; ++s) {
      __syncthreads();
      if ((wave >> 1) == (s >> 1)) {
#pragma unroll
        for (int mi = 0; mi < 2; ++mi)
#pragma unroll
          for (int n = 0; n < 4; ++n)
#pragma unroll
            for (int r = 0; r < 4; ++r) {
              int m = (s & 1) * 2 + mi;
              Csf[(mi * 16 + cr + r) * 128 + wc + n * 16 + cc] = acc[m][n][r];
            }
      }
      __syncthreads();
#pragma unroll
      for (int i = 0; i < 4; ++i) {
        int idx = i * 256 + tid;
        int row = idx >> 5, ch = idx & 31;
        float4 v = *(const float4*)&Csf[row * 128 + ch * 4];
        *(float4*)(C + (size_t)(bm + s * 32 + row) * N + bn + ch * 4) = v;
      }
    }
  }
}

// ---------------------------------------------------------------------------
// K3: MFMA neighborhood attention (unchanged)
// ---------------------------------------------------------------------------
__global__ __launch_bounds__(256) void attn_kernel(
    const ushort* __restrict__ qkv, ushort* __restrict__ outb) {
  __shared__ ushort lds[24576];          // 48 KB
  ushort* K_s  = lds;                    // [192 k][64 d], chunk swz c^(kr&7)
  ushort* Vt_s = lds + 12288;            // [64 d][192 k], chunk low3 ^ (d&7)^((d>>3)&7)
  ushort* P_s  = lds;                    // [64 q][192 k], chunk low3 ^ (q&7)
  ushort* O_s  = lds + 12288;            // [64 q][68 d-stride]

  const int tid = threadIdx.x;
  const int wave = tid >> 6;
  const int lane = tid & 63;
  const int lin = blockIdx.x;
  const int bid = (lin & 7) * 256 + (lin >> 3);   // XCD-chunked (2048 % 8 == 0)
  // bid = ((b*8 + n)*16 + th)*8 + tw
  const int tw = bid & 7, th = (bid >> 3) & 15, n = (bid >> 7) & 7, b = bid >> 10;
  const int hb = th * 2, wb = tw * 4;
  const int hb0 = max(hb - 1, 0), wb0 = max(wb - 1, 0);
  const int lm = lane & 15, g4 = lane >> 4;

  // ---- V: reg-stage 6 chunks/thread (plain) ----
  float4 vreg[6];
#pragma unroll
  for (int it = 0; it < 6; ++it) {
    int c = it * 256 + tid;
    int kr = c >> 3, gv = c & 7;
    int sc = kr >> 3, t = kr & 7;
    int kh = sc / 6, kw = sc - kh * 6;
    int hh = min(hb0 + kh, 31), ww = min(wb0 + kw, 31);
    size_t m = (((size_t)(b * 8 + t) * 32 + hh) * 32 + ww);
    vreg[it] = *(const float4*)(qkv + m * C3 + n * 192 + 128 + gv * 8);
  }

  // ---- K: global_load_lds, source-side XOR swz (1536 chunks) ----
#pragma unroll
  for (int it = 0; it < 6; ++it) {
    int c = it * 256 + tid;
    int kr = c >> 3, g = (c & 7) ^ (kr & 7);
    int sc = kr >> 3, t = kr & 7;
    int kh = sc / 6, kw = sc - kh * 6;
    int hh = min(hb0 + kh, 31), ww = min(wb0 + kw, 31);
    size_t m = (((size_t)(b * 8 + t) * 32 + hh) * 32 + ww);
    const ushort* srcK = qkv + m * C3 + n * 192 + 64 + g * 8;
    ushort* dstK = K_s + (size_t)(it * 256 + wave * 64) * 8;
    __builtin_amdgcn_global_load_lds((gbl_ptr_t)(const void*)srcK, (lds_ptr_t)dstK, 16, 0, 0);
  }

  // ---- Q: wave's 16-q fragment direct from global ----
  short8 bq[2];
  {
    int q = wave * 16 + lm;
    int tq = q >> 3, p = q & 7;
    size_t mq = (((size_t)(b * 8 + tq) * 32 + (hb + (p >> 2))) * 32 + (wb + (p & 3)));
    const ushort* qp = qkv + mq * C3 + n * 192;
#pragma unroll
    for (int kk = 0; kk < 2; ++kk)
      bq[kk] = *(const short8*)(qp + (kk * 4 + g4) * 8);
  }

  __syncthreads();  // bar1: K staged (drains V/Q loads too)

  // ---- Vt transposed scatter-write (overlaps St on LDS pipe) ----
#pragma unroll
  for (int it = 0; it < 6; ++it) {
    int c = it * 256 + tid;
    int kr = c >> 3, gv = c & 7;
    int ck = kr >> 3, kin = kr & 7;
    union { float4 f; ushort u[8]; } vv;
    vv.f = vreg[it];
#pragma unroll
    for (int j = 0; j < 8; ++j) {
      int d = gv * 8 + j;
      int cks = ck ^ ((j ^ gv) & 7);       // group-preserving low-3 XOR
      Vt_s[d * 192 + cks * 8 + kin] = vv.u[j];
    }
  }

  // ---- St = K·Q^T : wave computes ONLY its 16 q (no redundancy) ----
  f32x4 st[12];
#pragma unroll
  for (int kf = 0; kf < 12; ++kf) st[kf] = (f32x4){0.f, 0.f, 0.f, 0.f};
#pragma unroll
  for (int kk = 0; kk < 2; ++kk)
#pragma unroll
    for (int kf = 0; kf < 12; ++kf) {
      int kr = kf * 16 + lm;
      short8 a = *(const short8*)&K_s[kr * 64 + (((kk * 4 + g4) ^ (kr & 7)) * 8)];
      st[kf] = __builtin_amdgcn_mfma_f32_16x16x32_bf16(a, bq[kk], st[kf], 0, 0, 0);
    }

  // ---- mask + softmax (lane: q-col = wave*16+lm; k = kf*16 + g4*4 + r) ----
  const int p = lm & 7;                   // (wave*16+lm)&7 == lm&7
  const int qh = hb + (p >> 2), qw = wb + (p & 3);
  const int loh = min(max(qh - 1, 0), 29), low = min(max(qw - 1, 0), 29);
  uint mk = 0;
#pragma unroll
  for (int kf = 0; kf < 12; ++kf) {
    int sc = kf * 2 + (g4 >> 1);
    int kh = sc / 6, kw = sc - kh * 6;
    int khg = hb0 + kh, kwg = wb0 + kw;   // nominal (unclamped) position
    bool ok = (khg >= loh) && (khg <= loh + 2) && (kwg >= low) && (kwg <= low + 2);
    mk |= (uint)ok << kf;
  }
  const float scale = 0.125f;
#pragma unroll
  for (int kf = 0; kf < 12; ++kf) {
    bool ok = (mk >> kf) & 1;
#pragma unroll
    for (int r = 0; r < 4; ++r)
      st[kf][r] = ok ? st[kf][r] * scale : -1e30f;
  }
  float mx = -1e30f;
#pragma unroll
  for (int kf = 0; kf < 12; ++kf)
#pragma unroll
    for (int r = 0; r < 4; ++r) mx = fmaxf(mx, st[kf][r]);
  mx = fmaxf(mx, __shfl_xor(mx, 16));
  mx = fmaxf(mx, __shfl_xor(mx, 32));
  float s = 0.f;
#pragma unroll
  for (int kf = 0; kf < 12; ++kf)
#pragma unroll
    for (int r = 0; r < 4; ++r) {
      float e = __expf(st[kf][r] - mx);
      st[kf][r] = e;
      s += e;
    }
  s += __shfl_xor(s, 16);
  s += __shfl_xor(s, 32);
  const float inv = 1.f / s;
  __syncthreads();  // bar2: K reads done (P may overwrite), Vt writes visible

  // ---- P write: wave-disjoint rows q = wave*16+lm; compile-time st idx ----
  {
    const int q = wave * 16 + lm;
    ushort* Prow = P_s + q * 192 + (g4 & 1) * 4;
#pragma unroll
    for (int kf = 0; kf < 12; ++kf) {
      uint lo = (uint)f2bf(st[kf][0] * inv) | ((uint)f2bf(st[kf][1] * inv) << 16);
      uint hi = (uint)f2bf(st[kf][2] * inv) | ((uint)f2bf(st[kf][3] * inv) << 16);
      int ck = kf * 2 + (g4 >> 1);
      int cks = ck ^ (lm & 7);            // group-preserving (q&7 == lm&7)
      uint2 val; val.x = lo; val.y = hi;
      *(uint2*)(Prow + cks * 8) = val;
    }
  }
  __syncthreads();  // bar3: P ready

  // ---- PV: wave owns d-block wave*16; out[q][d] for all 4 q-frags ----
  f32x4 ao0 = (f32x4){0.f, 0.f, 0.f, 0.f};
  f32x4 ao1 = (f32x4){0.f, 0.f, 0.f, 0.f};
  f32x4 ao2 = (f32x4){0.f, 0.f, 0.f, 0.f};
  f32x4 ao3 = (f32x4){0.f, 0.f, 0.f, 0.f};
  const int drow = wave * 16 + lm;
  const int dsw = (lm & 7) ^ ((wave * 2 + (lm >> 3)) & 7);
#pragma unroll
  for (int kk = 0; kk < 6; ++kk) {
    int ch = kk * 4 + g4;
    short8 bv = *(const short8*)&Vt_s[drow * 192 + ((ch ^ dsw) * 8)];
    int pch = (ch ^ (lm & 7)) * 8;
    short8 av0 = *(const short8*)&P_s[(0 * 16 + lm) * 192 + pch];
    short8 av1 = *(const short8*)&P_s[(1 * 16 + lm) * 192 + pch];
    short8 av2 = *(const short8*)&P_s[(2 * 16 + lm) * 192 + pch];
    short8 av3 = *(const short8*)&P_s[(3 * 16 + lm) * 192 + pch];
    ao0 = __builtin_amdgcn_mfma_f32_16x16x32_bf16(av0, bv, ao0, 0, 0, 0);
    ao1 = __builtin_amdgcn_mfma_f32_16x16x32_bf16(av1, bv, ao1, 0, 0, 0);
    ao2 = __builtin_amdgcn_mfma_f32_16x16x32_bf16(av2, bv, ao2, 0, 0, 0);
    ao3 = __builtin_amdgcn_mfma_f32_16x16x32_bf16(av3, bv, ao3, 0, 0, 0);
  }
  __syncthreads();  // bar4: PV's Vt/P reads done; O may overwrite Vt region

  // ---- epilogue: O via LDS (stride 68), coalesced bf16 store ----
#pragma unroll
  for (int r = 0; r < 4; ++r) {
    O_s[(0 * 16 + g4 * 4 + r) * 68 + (wave * 16 + lm)] = f2bf(ao0[r]);
    O_s[(1 * 16 + g4 * 4 + r) * 68 + (wave * 16 + lm)] = f2bf(ao1[r]);
    O_s[(2 * 16 + g4 * 4 + r) * 68 + (wave * 16 + lm)] = f2bf(ao2[r]);
    O_s[(3 * 16 + g4 * 4 + r) * 68 + (wave * 16 + lm)] = f2bf(ao3[r]);
  }
  __syncthreads();  // bar5
#pragma unroll
  for (int i = 0; i < 2; ++i) {
    int idx = i * 256 + tid;
    int q = idx >> 3, c = idx & 7;
    short8 v = *(const short8*)&O_s[q * 68 + c * 8];
    int tq = q >> 3, pp = q & 7;
    size_t m = (((size_t)(b * 8 + tq) * 32 + (hb + (pp >> 2))) * 32 + (wb + (pp & 3)));
    *(short8*)(outb + m * (size_t)C_ + n * 64 + c * 8) = v;
  }
}

// ---------------------------------------------------------------------------
extern "C" void kernel_launch(void* const* d_in, const int* in_sizes, int n_in,
                              void* d_out, int out_size, void* d_ws, size_t ws_size,
                              hipStream_t stream) {
  const float* x     = (const float*)d_in[0];
  const float* freqs = (const float*)d_in[1];
  const float* w_in  = (const float*)d_in[2];
  const float* w_out = (const float*)d_in[3];
  const float* qg    = (const float*)d_in[4];
  const float* kg    = (const float*)d_in[5];
  float* out = (float*)d_out;

  char* ws = (char*)d_ws;
  ushort* qkv   = (ushort*)ws;                                    // 50.3 MB bf16
  ushort* xb    = (ushort*)(ws + (size_t)NTOK * C3 * 2);          // 16.8 MB
  ushort* wib   = xb + (size_t)NTOK * C_;                         // 1.5 MB
  ushort* wob   = wib + (size_t)C3 * C_;                          // 0.5 MB
  ushort* attnb = wob + (size_t)C_ * C_;                          // 16.8 MB
  // cos/sin table overlays attnb (2 MB): read only during gemm1, attnb is
  // written only later by attn_kernel (stream-ordered, no conflict).
  float2* csn = (float2*)attnb;

  // 0) fused casts + sincos table (128 extra blocks)
  cast3_kernel<<<4736, 256, 0, stream>>>(x, w_in, w_out, freqs, xb, wib, wob, csn);

  // 1) qkv = x @ w_in^T with fused RMSNorm+RoPE epilogue (bf16 out).
  //    grid 1536 = 128 bm x 12 bn, XCD-chunked.
  gemm_qkv_fused<<<1536, 256, 0, stream>>>(xb, wib, qkv, C3, C_, 12, csn, qg, kg);
  // 2) MFMA neighborhood attention -> attnb. grid 2048 = 2b x 8n x 16th x 8tw.
  attn_kernel<<<2048, 256, 0, stream>>>(qkv, attnb);
  // 3) out = attn @ w_out^T (fp32 out). grid 512 = 128 bm x 4 bn.
  gemm_bt_bf16<false><<<512, 256, 0, stream>>>(attnb, wob, out, C_, C_, 4);
}

// Round 3
// 100.931 us; speedup vs baseline: 1.3118x; 1.3118x over previous
//
#include <hip/hip_runtime.h>
#include <hip/hip_bf16.h>
#include <math.h>

#define NH 8
#define C_ 512
#define C3 1536
#define NTOK 16384   // b*t*h*w = 2*8*32*32

typedef __attribute__((ext_vector_type(8))) short short8;
typedef __attribute__((ext_vector_type(4))) float f32x4;
typedef __attribute__((address_space(3))) void* lds_ptr_t;
typedef const __attribute__((address_space(1))) void* gbl_ptr_t;

static __device__ __forceinline__ ushort f2bf(float f) {
  __hip_bfloat16 h = __float2bfloat16(f);
  return *reinterpret_cast<ushort*>(&h);
}
static __device__ __forceinline__ float bf2f(ushort u) {
  uint t = ((uint)u) << 16;
  float f;
  __builtin_memcpy(&f, &t, 4);
  return f;
}

// ---------------------------------------------------------------------------
// K0: fused fp32 -> bf16 cast for x, w_in, w_out PLUS cos/sin table for rope.
// csn[idx] = (cosf(freqs[idx]), sinf(freqs[idx])), idx over 8*32*32*32 = 262144.
// ---------------------------------------------------------------------------
__global__ __launch_bounds__(256) void cast3_kernel(
    const float* __restrict__ x, const float* __restrict__ wi,
    const float* __restrict__ wo, const float* __restrict__ fr,
    ushort* __restrict__ xb, ushort* __restrict__ wib,
    ushort* __restrict__ wob, float2* __restrict__ csn) {
  const int blk = blockIdx.x;
  if (blk >= 4608) {   // 128 blocks: sincos table (8 entries/thread)
    int i = (blk - 4608) * 256 + threadIdx.x;
    const float4* fp = (const float4*)fr + (size_t)i * 2;
    float4 a = fp[0], b = fp[1];
    float v[8] = {a.x, a.y, a.z, a.w, b.x, b.y, b.z, b.w};
    float2 o[8];
#pragma unroll
    for (int j = 0; j < 8; ++j) { o[j].x = cosf(v[j]); o[j].y = sinf(v[j]); }
    float4* op = (float4*)(csn + (size_t)i * 8);
    op[0] = make_float4(o[0].x, o[0].y, o[1].x, o[1].y);
    op[1] = make_float4(o[2].x, o[2].y, o[3].x, o[3].y);
    op[2] = make_float4(o[4].x, o[4].y, o[5].x, o[5].y);
    op[3] = make_float4(o[6].x, o[6].y, o[7].x, o[7].y);
    return;
  }
  const float* src;
  ushort* dst;
  int i;
  if (blk < 4096)      { src = x;  dst = xb;  i = blk * 256 + threadIdx.x; }
  else if (blk < 4480) { src = wi; dst = wib; i = (blk - 4096) * 256 + threadIdx.x; }
  else                 { src = wo; dst = wob; i = (blk - 4480) * 256 + threadIdx.x; }
  const float4* p = (const float4*)src + (size_t)i * 2;
  float4 v0 = p[0], v1 = p[1];
  union { ushort u[8]; uint4 v; } r;
  r.u[0] = f2bf(v0.x); r.u[1] = f2bf(v0.y); r.u[2] = f2bf(v0.z); r.u[3] = f2bf(v0.w);
  r.u[4] = f2bf(v1.x); r.u[5] = f2bf(v1.y); r.u[6] = f2bf(v1.z); r.u[7] = f2bf(v1.w);
  *(uint4*)(dst + (size_t)i * 8) = r.v;
}

// ---------------------------------------------------------------------------
// Shared 128x128x32 GEMM main loop pieces (proven R8 structure):
// prefetch double-buffer, T2 source swizzle, T1 XCD swizzle.
// ---------------------------------------------------------------------------
#define TBM 128
#define TBN 128
#define TBK 32
#define TILE_U ((TBM + TBN) * TBK)

static __device__ __forceinline__ void stage_tile(
    const ushort* __restrict__ A, const ushort* __restrict__ B,
    ushort* As, ushort* Bs, int bm, int bn, int K, int k0, int tid) {
#pragma unroll
  for (int it = 0; it < 2; ++it) {
    int c = it * 256 + tid;
    int row = c >> 2;
    int sk = ((c & 3) ^ ((row >> 1) & 3)) * 8;
    __builtin_amdgcn_global_load_lds(
        (gbl_ptr_t)(const void*)(A + (size_t)(bm + row) * K + k0 + sk),
        (lds_ptr_t)(As + (size_t)c * 8), 16, 0, 0);
    __builtin_amdgcn_global_load_lds(
        (gbl_ptr_t)(const void*)(B + (size_t)(bn + row) * K + k0 + sk),
        (lds_ptr_t)(Bs + (size_t)c * 8), 16, 0, 0);
  }
}

// ---------------------------------------------------------------------------
// K1: qkv GEMM with FUSED RMSNorm + RoPE epilogue (bf16 out), LOW-VGPR variant.
// Epilogue re-tiled: 8 threads per (row, 128 cols), each owns 16 channels
// (one uint4x2 = 32 B), x2 reps for 64 rows. Sum-of-squares over a 64-ch head
// chunk via shfl_xor(1)+shfl_xor(2) across the 4 threads of the chunk.
// No f[32] array: floats unpacked on demand from the 8-VGPR raw union (bf2f =
// 1 shift). cos/sin read 8 B/step from the precomputed table. Numerics are
// bit-identical to the R2 fused version (which passed); only tiling changed.
// ---------------------------------------------------------------------------
#define CSTR 136

__global__ __launch_bounds__(256) void gemm_qkv_fused(
    const ushort* __restrict__ A, const ushort* __restrict__ B,
    ushort* __restrict__ C, int N, int K, int GX,
    const float2* __restrict__ csn, const float* __restrict__ qg,
    const float* __restrict__ kg) {
  __shared__ ushort smem[2 * TILE_U];
  __shared__ float gsh[128];
  const int tid  = threadIdx.x;
  const int wave = tid >> 6;
  const int lane = tid & 63;
  const int nwg = gridDim.x;
  const int wg = (blockIdx.x & 7) * (nwg >> 3) + (blockIdx.x >> 3);
  const int bm = (wg / GX) * TBM;
  const int bn = (wg % GX) * TBN;
  const int wr = (wave >> 1) * 64;
  const int wc = (wave & 1) * 64;
  const int lm = lane & 15;
  const int g4 = lane >> 4;

  if (tid < 128) gsh[tid] = (tid < 64) ? qg[tid] : kg[tid - 64];

  f32x4 acc[4][4];
#pragma unroll
  for (int m = 0; m < 4; ++m)
#pragma unroll
    for (int n = 0; n < 4; ++n) acc[m][n] = (f32x4){0.f, 0.f, 0.f, 0.f};

  const int ko = (g4 ^ ((lm >> 1) & 3)) * 8;

  const int nt = K / TBK;
  stage_tile(A, B, smem, smem + TBM * TBK, bm, bn, K, 0, tid);
  __syncthreads();

  int cur = 0;
  for (int t = 0; t < nt; ++t) {
    if (t + 1 < nt) {
      ushort* Asn = smem + (cur ^ 1) * TILE_U;
      stage_tile(A, B, Asn, Asn + TBM * TBK, bm, bn, K, (t + 1) * TBK, tid);
    }
    const ushort* As = smem + cur * TILE_U;
    const ushort* Bs = As + TBM * TBK;
    short8 av[4], bv[4];
#pragma unroll
    for (int m = 0; m < 4; ++m)
      av[m] = *(const short8*)&As[(wr + m * 16 + lm) * TBK + ko];
#pragma unroll
    for (int n = 0; n < 4; ++n)
      bv[n] = *(const short8*)&Bs[(wc + n * 16 + lm) * TBK + ko];
#pragma unroll
    for (int m = 0; m < 4; ++m)
#pragma unroll
      for (int n = 0; n < 4; ++n)
        acc[m][n] = __builtin_amdgcn_mfma_f32_16x16x32_bf16(av[m], bv[n], acc[m][n], 0, 0, 0);
    __syncthreads();
    cur ^= 1;
  }

  // ---- fused epilogue (low-VGPR) ----
  const int cr = g4 * 4;
  const int cc = lm;
  ushort* Cs = smem;

#pragma unroll
  for (int h = 0; h < 2; ++h) {
    __syncthreads();
    if ((wave >> 1) == h) {
#pragma unroll
      for (int m = 0; m < 4; ++m)
#pragma unroll
        for (int n = 0; n < 4; ++n)
#pragma unroll
          for (int r = 0; r < 4; ++r)
            Cs[(m * 16 + cr + r) * CSTR + wc + n * 16 + cc] = f2bf(acc[m][n][r]);
    }
    __syncthreads();
#pragma unroll
    for (int rep = 0; rep < 2; ++rep) {
      const int task = rep * 256 + tid;
      const int row  = task >> 3;          // 0..63
      const int sub  = task & 7;
      const int cg   = sub >> 2;           // which 64-chunk of the 128 cols
      const int quar = sub & 3;            // 16-channel quarter of the chunk
      const int colg = bn + cg * 64;
      const int type = (colg % 192) >> 6;  // 0=q, 1=k, 2=v
      const int gofs = (type & 1) * 64;

      union { uint4 q[2]; ushort u[16]; } L;
      {
        const uint4* srcp = (const uint4*)&Cs[row * CSTR + cg * 64 + quar * 16];
        L.q[0] = srcp[0]; L.q[1] = srcp[1];
      }
      float ss = 0.f;
#pragma unroll
      for (int j = 0; j < 16; ++j) { float fv = bf2f(L.u[j]); ss += fv * fv; }
      ss += __shfl_xor(ss, 1);
      ss += __shfl_xor(ss, 2);
      const float rn = rsqrtf(ss * (1.f / 64.f) + 1e-6f);

      const int tokm = bm + h * 64 + row;
      const int tloc = (tokm >> 10) & 7;
      const float2* cb =
          csn + (((size_t)((tloc << 10) | (tokm & 1023))) << 5) + quar * 8;

      union { uint4 q[2]; ushort u[16]; } O;
#pragma unroll
      for (int dj = 0; dj < 8; ++dj) {
        float2 cs2 = cb[dj];
        float2 gg = *(const float2*)&gsh[gofs + (quar * 8 + dj) * 2];
        float xe = bf2f(L.u[2 * dj])     * rn * gg.x;
        float xo = bf2f(L.u[2 * dj + 1]) * rn * gg.y;
        O.u[2 * dj]     = f2bf(xe * cs2.x - xo * cs2.y);
        O.u[2 * dj + 1] = f2bf(xe * cs2.y + xo * cs2.x);
      }
      if (type == 2) { O.q[0] = L.q[0]; O.q[1] = L.q[1]; }
      uint4* dst = (uint4*)(C + (size_t)tokm * N + colg + quar * 16);
      dst[0] = O.q[0]; dst[1] = O.q[1];
    }
  }
}

// ---------------------------------------------------------------------------
// K1b: plain NT GEMM (fp32 out) for the output projection (unchanged).
// ---------------------------------------------------------------------------
template <bool BF16OUT>
__global__ __launch_bounds__(256) void gemm_bt_bf16(
    const ushort* __restrict__ A, const ushort* __restrict__ B,
    void* __restrict__ Cv, int N, int K, int GX) {
  __shared__ ushort smem[2 * TILE_U];
  const int tid  = threadIdx.x;
  const int wave = tid >> 6;
  const int lane = tid & 63;
  const int nwg = gridDim.x;
  const int wg = (blockIdx.x & 7) * (nwg >> 3) + (blockIdx.x >> 3);
  const int bm = (wg / GX) * TBM;
  const int bn = (wg % GX) * TBN;
  const int wr = (wave >> 1) * 64;
  const int wc = (wave & 1) * 64;
  const int lm = lane & 15;
  const int g4 = lane >> 4;

  f32x4 acc[4][4];
#pragma unroll
  for (int m = 0; m < 4; ++m)
#pragma unroll
    for (int n = 0; n < 4; ++n) acc[m][n] = (f32x4){0.f, 0.f, 0.f, 0.f};

  const int ko = (g4 ^ ((lm >> 1) & 3)) * 8;

  const int nt = K / TBK;
  stage_tile(A, B, smem, smem + TBM * TBK, bm, bn, K, 0, tid);
  __syncthreads();

  int cur = 0;
  for (int t = 0; t < nt; ++t) {
    if (t + 1 < nt) {
      ushort* Asn = smem + (cur ^ 1) * TILE_U;
      stage_tile(A, B, Asn, Asn + TBM * TBK, bm, bn, K, (t + 1) * TBK, tid);
    }
    const ushort* As = smem + cur * TILE_U;
    const ushort* Bs = As + TBM * TBK;
    short8 av[4], bv[4];
#pragma unroll
    for (int m = 0; m < 4; ++m)
      av[m] = *(const short8*)&As[(wr + m * 16 + lm) * TBK + ko];
#pragma unroll
    for (int n = 0; n < 4; ++n)
      bv[n] = *(const short8*)&Bs[(wc + n * 16 + lm) * TBK + ko];
#pragma unroll
    for (int m = 0; m < 4; ++m)
#pragma unroll
      for (int n = 0; n < 4; ++n)
        acc[m][n] = __builtin_amdgcn_mfma_f32_16x16x32_bf16(av[m], bv[n], acc[m][n], 0, 0, 0);
    __syncthreads();
    cur ^= 1;
  }

  const int cr = g4 * 4;
  const int cc = lm;

  if (BF16OUT) {
    ushort* Cs = smem;
    ushort* C = (ushort*)Cv;
#pragma unroll
    for (int h = 0; h < 2; ++h) {
      __syncthreads();
      if ((wave >> 1) == h) {
#pragma unroll
        for (int m = 0; m < 4; ++m)
#pragma unroll
          for (int n = 0; n < 4; ++n)
#pragma unroll
            for (int r = 0; r < 4; ++r)
              Cs[(m * 16 + cr + r) * 128 + wc + n * 16 + cc] = f2bf(acc[m][n][r]);
      }
      __syncthreads();
#pragma unroll
      for (int i = 0; i < 4; ++i) {
        int idx = i * 256 + tid;
        int row = idx >> 4, ch = idx & 15;
        uint4 v = *(const uint4*)&Cs[row * 128 + ch * 8];
        *(uint4*)(C + (size_t)(bm + h * 64 + row) * N + bn + ch * 8) = v;
      }
    }
  } else {
    float* Csf = (float*)smem;
    float* C = (float*)Cv;
#pragma unroll
    for (int s = 0; s < 4; ++s) {
      __syncthreads();
      if ((wave >> 1) == (s >> 1)) {
#pragma unroll
        for (int mi = 0; mi < 2; ++mi)
#pragma unroll
          for (int n = 0; n < 4; ++n)
#pragma unroll
            for (int r = 0; r < 4; ++r) {
              int m = (s & 1) * 2 + mi;
              Csf[(mi * 16 + cr + r) * 128 + wc + n * 16 + cc] = acc[m][n][r];
            }
      }
      __syncthreads();
#pragma unroll
      for (int i = 0; i < 4; ++i) {
        int idx = i * 256 + tid;
        int row = idx >> 5, ch = idx & 31;
        float4 v = *(const float4*)&Csf[row * 128 + ch * 4];
        *(float4*)(C + (size_t)(bm + s * 32 + row) * N + bn + ch * 4) = v;
      }
    }
  }
}

// ---------------------------------------------------------------------------
// K3: MFMA neighborhood attention (unchanged)
// ---------------------------------------------------------------------------
__global__ __launch_bounds__(256) void attn_kernel(
    const ushort* __restrict__ qkv, ushort* __restrict__ outb) {
  __shared__ ushort lds[24576];          // 48 KB
  ushort* K_s  = lds;                    // [192 k][64 d], chunk swz c^(kr&7)
  ushort* Vt_s = lds + 12288;            // [64 d][192 k], chunk low3 ^ (d&7)^((d>>3)&7)
  ushort* P_s  = lds;                    // [64 q][192 k], chunk low3 ^ (q&7)
  ushort* O_s  = lds + 12288;            // [64 q][68 d-stride]

  const int tid = threadIdx.x;
  const int wave = tid >> 6;
  const int lane = tid & 63;
  const int lin = blockIdx.x;
  const int bid = (lin & 7) * 256 + (lin >> 3);   // XCD-chunked (2048 % 8 == 0)
  // bid = ((b*8 + n)*16 + th)*8 + tw
  const int tw = bid & 7, th = (bid >> 3) & 15, n = (bid >> 7) & 7, b = bid >> 10;
  const int hb = th * 2, wb = tw * 4;
  const int hb0 = max(hb - 1, 0), wb0 = max(wb - 1, 0);
  const int lm = lane & 15, g4 = lane >> 4;

  // ---- V: reg-stage 6 chunks/thread (plain) ----
  float4 vreg[6];
#pragma unroll
  for (int it = 0; it < 6; ++it) {
    int c = it * 256 + tid;
    int kr = c >> 3, gv = c & 7;
    int sc = kr >> 3, t = kr & 7;
    int kh = sc / 6, kw = sc - kh * 6;
    int hh = min(hb0 + kh, 31), ww = min(wb0 + kw, 31);
    size_t m = (((size_t)(b * 8 + t) * 32 + hh) * 32 + ww);
    vreg[it] = *(const float4*)(qkv + m * C3 + n * 192 + 128 + gv * 8);
  }

  // ---- K: global_load_lds, source-side XOR swz (1536 chunks) ----
#pragma unroll
  for (int it = 0; it < 6; ++it) {
    int c = it * 256 + tid;
    int kr = c >> 3, g = (c & 7) ^ (kr & 7);
    int sc = kr >> 3, t = kr & 7;
    int kh = sc / 6, kw = sc - kh * 6;
    int hh = min(hb0 + kh, 31), ww = min(wb0 + kw, 31);
    size_t m = (((size_t)(b * 8 + t) * 32 + hh) * 32 + ww);
    const ushort* srcK = qkv + m * C3 + n * 192 + 64 + g * 8;
    ushort* dstK = K_s + (size_t)(it * 256 + wave * 64) * 8;
    __builtin_amdgcn_global_load_lds((gbl_ptr_t)(const void*)srcK, (lds_ptr_t)dstK, 16, 0, 0);
  }

  // ---- Q: wave's 16-q fragment direct from global ----
  short8 bq[2];
  {
    int q = wave * 16 + lm;
    int tq = q >> 3, p = q & 7;
    size_t mq = (((size_t)(b * 8 + tq) * 32 + (hb + (p >> 2))) * 32 + (wb + (p & 3)));
    const ushort* qp = qkv + mq * C3 + n * 192;
#pragma unroll
    for (int kk = 0; kk < 2; ++kk)
      bq[kk] = *(const short8*)(qp + (kk * 4 + g4) * 8);
  }

  __syncthreads();  // bar1: K staged (drains V/Q loads too)

  // ---- Vt transposed scatter-write (overlaps St on LDS pipe) ----
#pragma unroll
  for (int it = 0; it < 6; ++it) {
    int c = it * 256 + tid;
    int kr = c >> 3, gv = c & 7;
    int ck = kr >> 3, kin = kr & 7;
    union { float4 f; ushort u[8]; } vv;
    vv.f = vreg[it];
#pragma unroll
    for (int j = 0; j < 8; ++j) {
      int d = gv * 8 + j;
      int cks = ck ^ ((j ^ gv) & 7);       // group-preserving low-3 XOR
      Vt_s[d * 192 + cks * 8 + kin] = vv.u[j];
    }
  }

  // ---- St = K·Q^T : wave computes ONLY its 16 q (no redundancy) ----
  f32x4 st[12];
#pragma unroll
  for (int kf = 0; kf < 12; ++kf) st[kf] = (f32x4){0.f, 0.f, 0.f, 0.f};
#pragma unroll
  for (int kk = 0; kk < 2; ++kk)
#pragma unroll
    for (int kf = 0; kf < 12; ++kf) {
      int kr = kf * 16 + lm;
      short8 a = *(const short8*)&K_s[kr * 64 + (((kk * 4 + g4) ^ (kr & 7)) * 8)];
      st[kf] = __builtin_amdgcn_mfma_f32_16x16x32_bf16(a, bq[kk], st[kf], 0, 0, 0);
    }

  // ---- mask + softmax (lane: q-col = wave*16+lm; k = kf*16 + g4*4 + r) ----
  const int p = lm & 7;                   // (wave*16+lm)&7 == lm&7
  const int qh = hb + (p >> 2), qw = wb + (p & 3);
  const int loh = min(max(qh - 1, 0), 29), low = min(max(qw - 1, 0), 29);
  uint mk = 0;
#pragma unroll
  for (int kf = 0; kf < 12; ++kf) {
    int sc = kf * 2 + (g4 >> 1);
    int kh = sc / 6, kw = sc - kh * 6;
    int khg = hb0 + kh, kwg = wb0 + kw;   // nominal (unclamped) position
    bool ok = (khg >= loh) && (khg <= loh + 2) && (kwg >= low) && (kwg <= low + 2);
    mk |= (uint)ok << kf;
  }
  const float scale = 0.125f;
#pragma unroll
  for (int kf = 0; kf < 12; ++kf) {
    bool ok = (mk >> kf) & 1;
#pragma unroll
    for (int r = 0; r < 4; ++r)
      st[kf][r] = ok ? st[kf][r] * scale : -1e30f;
  }
  float mx = -1e30f;
#pragma unroll
  for (int kf = 0; kf < 12; ++kf)
#pragma unroll
    for (int r = 0; r < 4; ++r) mx = fmaxf(mx, st[kf][r]);
  mx = fmaxf(mx, __shfl_xor(mx, 16));
  mx = fmaxf(mx, __shfl_xor(mx, 32));
  float s = 0.f;
#pragma unroll
  for (int kf = 0; kf < 12; ++kf)
#pragma unroll
    for (int r = 0; r < 4; ++r) {
      float e = __expf(st[kf][r] - mx);
      st[kf][r] = e;
      s += e;
    }
  s += __shfl_xor(s, 16);
  s += __shfl_xor(s, 32);
  const float inv = 1.f / s;
  __syncthreads();  // bar2: K reads done (P may overwrite), Vt writes visible

  // ---- P write: wave-disjoint rows q = wave*16+lm; compile-time st idx ----
  {
    const int q = wave * 16 + lm;
    ushort* Prow = P_s + q * 192 + (g4 & 1) * 4;
#pragma unroll
    for (int kf = 0; kf < 12; ++kf) {
      uint lo = (uint)f2bf(st[kf][0] * inv) | ((uint)f2bf(st[kf][1] * inv) << 16);
      uint hi = (uint)f2bf(st[kf][2] * inv) | ((uint)f2bf(st[kf][3] * inv) << 16);
      int ck = kf * 2 + (g4 >> 1);
      int cks = ck ^ (lm & 7);            // group-preserving (q&7 == lm&7)
      uint2 val; val.x = lo; val.y = hi;
      *(uint2*)(Prow + cks * 8) = val;
    }
  }
  __syncthreads();  // bar3: P ready

  // ---- PV: wave owns d-block wave*16; out[q][d] for all 4 q-frags ----
  f32x4 ao0 = (f32x4){0.f, 0.f, 0.f, 0.f};
  f32x4 ao1 = (f32x4){0.f, 0.f, 0.f, 0.f};
  f32x4 ao2 = (f32x4){0.f, 0.f, 0.f, 0.f};
  f32x4 ao3 = (f32x4){0.f, 0.f, 0.f, 0.f};
  const int drow = wave * 16 + lm;
  const int dsw = (lm & 7) ^ ((wave * 2 + (lm >> 3)) & 7);
#pragma unroll
  for (int kk = 0; kk < 6; ++kk) {
    int ch = kk * 4 + g4;
    short8 bv = *(const short8*)&Vt_s[drow * 192 + ((ch ^ dsw) * 8)];
    int pch = (ch ^ (lm & 7)) * 8;
    short8 av0 = *(const short8*)&P_s[(0 * 16 + lm) * 192 + pch];
    short8 av1 = *(const short8*)&P_s[(1 * 16 + lm) * 192 + pch];
    short8 av2 = *(const short8*)&P_s[(2 * 16 + lm) * 192 + pch];
    short8 av3 = *(const short8*)&P_s[(3 * 16 + lm) * 192 + pch];
    ao0 = __builtin_amdgcn_mfma_f32_16x16x32_bf16(av0, bv, ao0, 0, 0, 0);
    ao1 = __builtin_amdgcn_mfma_f32_16x16x32_bf16(av1, bv, ao1, 0, 0, 0);
    ao2 = __builtin_amdgcn_mfma_f32_16x16x32_bf16(av2, bv, ao2, 0, 0, 0);
    ao3 = __builtin_amdgcn_mfma_f32_16x16x32_bf16(av3, bv, ao3, 0, 0, 0);
  }
  __syncthreads();  // bar4: PV's Vt/P reads done; O may overwrite Vt region

  // ---- epilogue: O via LDS (stride 68), coalesced bf16 store ----
#pragma unroll
  for (int r = 0; r < 4; ++r) {
    O_s[(0 * 16 + g4 * 4 + r) * 68 + (wave * 16 + lm)] = f2bf(ao0[r]);
    O_s[(1 * 16 + g4 * 4 + r) * 68 + (wave * 16 + lm)] = f2bf(ao1[r]);
    O_s[(2 * 16 + g4 * 4 + r) * 68 + (wave * 16 + lm)] = f2bf(ao2[r]);
    O_s[(3 * 16 + g4 * 4 + r) * 68 + (wave * 16 + lm)] = f2bf(ao3[r]);
  }
  __syncthreads();  // bar5
#pragma unroll
  for (int i = 0; i < 2; ++i) {
    int idx = i * 256 + tid;
    int q = idx >> 3, c = idx & 7;
    short8 v = *(const short8*)&O_s[q * 68 + c * 8];
    int tq = q >> 3, pp = q & 7;
    size_t m = (((size_t)(b * 8 + tq) * 32 + (hb + (pp >> 2))) * 32 + (wb + (pp & 3)));
    *(short8*)(outb + m * (size_t)C_ + n * 64 + c * 8) = v;
  }
}

// ---------------------------------------------------------------------------
extern "C" void kernel_launch(void* const* d_in, const int* in_sizes, int n_in,
                              void* d_out, int out_size, void* d_ws, size_t ws_size,
                              hipStream_t stream) {
  const float* x     = (const float*)d_in[0];
  const float* freqs = (const float*)d_in[1];
  const float* w_in  = (const float*)d_in[2];
  const float* w_out = (const float*)d_in[3];
  const float* qg    = (const float*)d_in[4];
  const float* kg    = (const float*)d_in[5];
  float* out = (float*)d_out;

  char* ws = (char*)d_ws;
  ushort* qkv   = (ushort*)ws;                                    // 50.3 MB bf16
  ushort* xb    = (ushort*)(ws + (size_t)NTOK * C3 * 2);          // 16.8 MB
  ushort* wib   = xb + (size_t)NTOK * C_;                         // 1.5 MB
  ushort* wob   = wib + (size_t)C3 * C_;                          // 0.5 MB
  ushort* attnb = wob + (size_t)C_ * C_;                          // 16.8 MB
  // cos/sin table overlays attnb (2 MB): read only during gemm1, attnb is
  // written only later by attn_kernel (stream-ordered, no conflict).
  float2* csn = (float2*)attnb;

  // 0) fused casts + sincos table (128 extra blocks)
  cast3_kernel<<<4736, 256, 0, stream>>>(x, w_in, w_out, freqs, xb, wib, wob, csn);

  // 1) qkv = x @ w_in^T with fused RMSNorm+RoPE epilogue (bf16 out).
  //    grid 1536 = 128 bm x 12 bn, XCD-chunked.
  gemm_qkv_fused<<<1536, 256, 0, stream>>>(xb, wib, qkv, C3, C_, 12, csn, qg, kg);
  // 2) MFMA neighborhood attention -> attnb. grid 2048 = 2b x 8n x 16th x 8tw.
  attn_kernel<<<2048, 256, 0, stream>>>(qkv, attnb);
  // 3) out = attn @ w_out^T (fp32 out). grid 512 = 128 bm x 4 bn.
  gemm_bt_bf16<false><<<512, 256, 0, stream>>>(attnb, wob, out, C_, C_, 4);
}

// Round 4
// 100.863 us; speedup vs baseline: 1.3126x; 1.0007x over previous
//
#include <hip/hip_runtime.h>
#include <hip/hip_bf16.h>
#include <math.h>

#define NH 8
#define C_ 512
#define C3 1536
#define NTOK 16384   // b*t*h*w = 2*8*32*32

typedef __attribute__((ext_vector_type(8))) short short8;
typedef __attribute__((ext_vector_type(4))) float f32x4;
typedef __attribute__((address_space(3))) void* lds_ptr_t;
typedef const __attribute__((address_space(1))) void* gbl_ptr_t;

static __device__ __forceinline__ ushort f2bf(float f) {
  __hip_bfloat16 h = __float2bfloat16(f);
  return *reinterpret_cast<ushort*>(&h);
}
static __device__ __forceinline__ float bf2f(ushort u) {
  uint t = ((uint)u) << 16;
  float f;
  __builtin_memcpy(&f, &t, 4);
  return f;
}

// ---------------------------------------------------------------------------
// K0: fused fp32 -> bf16 cast for x, w_in, w_out PLUS cos/sin table for rope.
// csn[idx] = (cosf(freqs[idx]), sinf(freqs[idx])), idx over 8*32*32*32 = 262144.
// Table lives in d_out scratch (overwritten later by gemm2; stream-ordered).
// ---------------------------------------------------------------------------
__global__ __launch_bounds__(256) void cast3_kernel(
    const float* __restrict__ x, const float* __restrict__ wi,
    const float* __restrict__ wo, const float* __restrict__ fr,
    ushort* __restrict__ xb, ushort* __restrict__ wib,
    ushort* __restrict__ wob, float2* __restrict__ csn) {
  const int blk = blockIdx.x;
  if (blk >= 4608) {   // 128 blocks: sincos table (8 entries/thread)
    int i = (blk - 4608) * 256 + threadIdx.x;
    const float4* fp = (const float4*)fr + (size_t)i * 2;
    float4 a = fp[0], b = fp[1];
    float v[8] = {a.x, a.y, a.z, a.w, b.x, b.y, b.z, b.w};
    float2 o[8];
#pragma unroll
    for (int j = 0; j < 8; ++j) { o[j].x = cosf(v[j]); o[j].y = sinf(v[j]); }
    float4* op = (float4*)(csn + (size_t)i * 8);
    op[0] = make_float4(o[0].x, o[0].y, o[1].x, o[1].y);
    op[1] = make_float4(o[2].x, o[2].y, o[3].x, o[3].y);
    op[2] = make_float4(o[4].x, o[4].y, o[5].x, o[5].y);
    op[3] = make_float4(o[6].x, o[6].y, o[7].x, o[7].y);
    return;
  }
  const float* src;
  ushort* dst;
  int i;
  if (blk < 4096)      { src = x;  dst = xb;  i = blk * 256 + threadIdx.x; }
  else if (blk < 4480) { src = wi; dst = wib; i = (blk - 4096) * 256 + threadIdx.x; }
  else                 { src = wo; dst = wob; i = (blk - 4480) * 256 + threadIdx.x; }
  const float4* p = (const float4*)src + (size_t)i * 2;
  float4 v0 = p[0], v1 = p[1];
  union { ushort u[8]; uint4 v; } r;
  r.u[0] = f2bf(v0.x); r.u[1] = f2bf(v0.y); r.u[2] = f2bf(v0.z); r.u[3] = f2bf(v0.w);
  r.u[4] = f2bf(v1.x); r.u[5] = f2bf(v1.y); r.u[6] = f2bf(v1.z); r.u[7] = f2bf(v1.w);
  *(uint4*)(dst + (size_t)i * 8) = r.v;
}

// ---------------------------------------------------------------------------
// bf16 NT GEMM via MFMA (proven R0 structure): 128x128x32 prefetch double-
// buffer, T2 source swizzle, T1 XCD-chunked block swizzle, LDS-staged epilogue.
// ---------------------------------------------------------------------------
#define TBM 128
#define TBN 128
#define TBK 32
#define TILE_U ((TBM + TBN) * TBK)

static __device__ __forceinline__ void stage_tile(
    const ushort* __restrict__ A, const ushort* __restrict__ B,
    ushort* As, ushort* Bs, int bm, int bn, int K, int k0, int tid) {
#pragma unroll
  for (int it = 0; it < 2; ++it) {
    int c = it * 256 + tid;
    int row = c >> 2;
    int sk = ((c & 3) ^ ((row >> 1) & 3)) * 8;
    __builtin_amdgcn_global_load_lds(
        (gbl_ptr_t)(const void*)(A + (size_t)(bm + row) * K + k0 + sk),
        (lds_ptr_t)(As + (size_t)c * 8), 16, 0, 0);
    __builtin_amdgcn_global_load_lds(
        (gbl_ptr_t)(const void*)(B + (size_t)(bn + row) * K + k0 + sk),
        (lds_ptr_t)(Bs + (size_t)c * 8), 16, 0, 0);
  }
}

template <bool BF16OUT>
__global__ __launch_bounds__(256) void gemm_bt_bf16(
    const ushort* __restrict__ A, const ushort* __restrict__ B,
    void* __restrict__ Cv, int N, int K, int GX) {
  __shared__ ushort smem[2 * TILE_U];
  const int tid  = threadIdx.x;
  const int wave = tid >> 6;
  const int lane = tid & 63;
  const int nwg = gridDim.x;
  const int wg = (blockIdx.x & 7) * (nwg >> 3) + (blockIdx.x >> 3);
  const int bm = (wg / GX) * TBM;
  const int bn = (wg % GX) * TBN;
  const int wr = (wave >> 1) * 64;
  const int wc = (wave & 1) * 64;
  const int lm = lane & 15;
  const int g4 = lane >> 4;

  f32x4 acc[4][4];
#pragma unroll
  for (int m = 0; m < 4; ++m)
#pragma unroll
    for (int n = 0; n < 4; ++n) acc[m][n] = (f32x4){0.f, 0.f, 0.f, 0.f};

  const int ko = (g4 ^ ((lm >> 1) & 3)) * 8;

  const int nt = K / TBK;
  stage_tile(A, B, smem, smem + TBM * TBK, bm, bn, K, 0, tid);
  __syncthreads();

  int cur = 0;
  for (int t = 0; t < nt; ++t) {
    if (t + 1 < nt) {
      ushort* Asn = smem + (cur ^ 1) * TILE_U;
      stage_tile(A, B, Asn, Asn + TBM * TBK, bm, bn, K, (t + 1) * TBK, tid);
    }
    const ushort* As = smem + cur * TILE_U;
    const ushort* Bs = As + TBM * TBK;
    short8 av[4], bv[4];
#pragma unroll
    for (int m = 0; m < 4; ++m)
      av[m] = *(const short8*)&As[(wr + m * 16 + lm) * TBK + ko];
#pragma unroll
    for (int n = 0; n < 4; ++n)
      bv[n] = *(const short8*)&Bs[(wc + n * 16 + lm) * TBK + ko];
#pragma unroll
    for (int m = 0; m < 4; ++m)
#pragma unroll
      for (int n = 0; n < 4; ++n)
        acc[m][n] = __builtin_amdgcn_mfma_f32_16x16x32_bf16(av[m], bv[n], acc[m][n], 0, 0, 0);
    __syncthreads();
    cur ^= 1;
  }

  const int cr = g4 * 4;
  const int cc = lm;

  if (BF16OUT) {
    ushort* Cs = smem;
    ushort* C = (ushort*)Cv;
#pragma unroll
    for (int h = 0; h < 2; ++h) {
      __syncthreads();
      if ((wave >> 1) == h) {
#pragma unroll
        for (int m = 0; m < 4; ++m)
#pragma unroll
          for (int n = 0; n < 4; ++n)
#pragma unroll
            for (int r = 0; r < 4; ++r)
              Cs[(m * 16 + cr + r) * 128 + wc + n * 16 + cc] = f2bf(acc[m][n][r]);
      }
      __syncthreads();
#pragma unroll
      for (int i = 0; i < 4; ++i) {
        int idx = i * 256 + tid;
        int row = idx >> 4, ch = idx & 15;
        uint4 v = *(const uint4*)&Cs[row * 128 + ch * 8];
        *(uint4*)(C + (size_t)(bm + h * 64 + row) * N + bn + ch * 8) = v;
      }
    }
  } else {
    float* Csf = (float*)smem;
    float* C = (float*)Cv;
#pragma unroll
    for (int s = 0; s < 4; ++s) {
      __syncthreads();
      if ((wave >> 1) == (s >> 1)) {
#pragma unroll
        for (int mi = 0; mi < 2; ++mi)
#pragma unroll
          for (int n = 0; n < 4; ++n)
#pragma unroll
            for (int r = 0; r < 4; ++r) {
              int m = (s & 1) * 2 + mi;
              Csf[(mi * 16 + cr + r) * 128 + wc + n * 16 + cc] = acc[m][n][r];
            }
      }
      __syncthreads();
#pragma unroll
      for (int i = 0; i < 4; ++i) {
        int idx = i * 256 + tid;
        int row = idx >> 5, ch = idx & 31;
        float4 v = *(const float4*)&Csf[row * 128 + ch * 4];
        *(float4*)(C + (size_t)(bm + s * 32 + row) * N + bn + ch * 4) = v;
      }
    }
  }
}

// ---------------------------------------------------------------------------
// K3: MFMA neighborhood attention with FUSED RMSNorm + RoPE on q and k.
// qkv buffer holds RAW projections. K: reg-staged (float4), normed+roped
// in-register (row-sum via shfl_xor 1/2/4 across the 8 tid-consecutive
// threads of a k-row), then swizzled ds_write_b128 into K_s (same layout as
// the old source-swizzled global_load_lds). Q: normed in-register (row-sum
// via shfl_xor 16/32 across the 4 g4 groups holding one q-row). RoPE pairs
// are intra-chunk; cos/sin from precomputed table. V unchanged (no norm).
// ---------------------------------------------------------------------------
__global__ __launch_bounds__(256) void attn_kernel(
    const ushort* __restrict__ qkv, ushort* __restrict__ outb,
    const float* __restrict__ csn, const float* __restrict__ qg,
    const float* __restrict__ kg) {
  __shared__ ushort lds[24576];          // 48 KB
  ushort* K_s  = lds;                    // [192 k][64 d], chunk swz c^(kr&7)
  ushort* Vt_s = lds + 12288;            // [64 d][192 k], chunk low3 ^ (d&7)^((d>>3)&7)
  ushort* P_s  = lds;                    // [64 q][192 k], chunk low3 ^ (q&7)
  ushort* O_s  = lds + 12288;            // [64 q][68 d-stride]

  const int tid = threadIdx.x;
  const int wave = tid >> 6;
  const int lane = tid & 63;
  const int lin = blockIdx.x;
  const int bid = (lin & 7) * 256 + (lin >> 3);   // XCD-chunked (2048 % 8 == 0)
  // bid = ((b*8 + n)*16 + th)*8 + tw
  const int tw = bid & 7, th = (bid >> 3) & 15, n = (bid >> 7) & 7, b = bid >> 10;
  const int hb = th * 2, wb = tw * 4;
  const int hb0 = max(hb - 1, 0), wb0 = max(wb - 1, 0);
  const int lm = lane & 15, g4 = lane >> 4;

  // ---- V + K: reg-stage 6 chunks/thread each ----
  float4 vreg[6], kreg[6];
  int mi6[6];
#pragma unroll
  for (int it = 0; it < 6; ++it) {
    int c = it * 256 + tid;
    int kr = c >> 3, gv = c & 7;
    int sc = kr >> 3, t = kr & 7;
    int kh = sc / 6, kw = sc - kh * 6;
    int hh = min(hb0 + kh, 31), ww = min(wb0 + kw, 31);
    size_t m = (((size_t)(b * 8 + t) * 32 + hh) * 32 + ww);
    mi6[it] = (int)(m & 8191);
    const ushort* bp = qkv + m * C3 + n * 192;
    vreg[it] = *(const float4*)(bp + 128 + gv * 8);
    kreg[it] = *(const float4*)(bp + 64 + gv * 8);
  }

  // ---- Q: wave's 16-q fragment, fused norm + rope in-register ----
  short8 bq[2];
  {
    int q = wave * 16 + lm;
    int tq = q >> 3, p = q & 7;
    size_t mq = (((size_t)(b * 8 + tq) * 32 + (hb + (p >> 2))) * 32 + (wb + (p & 3)));
    const ushort* qp = qkv + mq * C3 + n * 192;
    union { short8 s; ushort u[8]; } Lq0, Lq1;
    Lq0.s = *(const short8*)(qp + g4 * 8);
    Lq1.s = *(const short8*)(qp + (4 + g4) * 8);
    float fq[16];
    float ssq = 0.f;
#pragma unroll
    for (int j = 0; j < 8; ++j) { fq[j] = bf2f(Lq0.u[j]); ssq += fq[j] * fq[j]; }
#pragma unroll
    for (int j = 0; j < 8; ++j) { fq[8 + j] = bf2f(Lq1.u[j]); ssq += fq[8 + j] * fq[8 + j]; }
    ssq += __shfl_xor(ssq, 16);
    ssq += __shfl_xor(ssq, 32);
    const float rq = rsqrtf(ssq * (1.f / 64.f) + 1e-6f);
    const int miq = (int)(mq & 8191);
#pragma unroll
    for (int kk = 0; kk < 2; ++kk) {
      const int ch0 = (kk * 4 + g4) * 8;
      const float4 ga = *(const float4*)(qg + ch0);
      const float4 gb = *(const float4*)(qg + ch0 + 4);
      const float* cbp = csn + (size_t)miq * 64 + ch0;
      const float4 c0 = *(const float4*)cbp;
      const float4 c1 = *(const float4*)(cbp + 4);
      const float* fv = &fq[kk * 8];
      union { short8 s; ushort u[8]; } O;
      float xe, xo;
      xe = fv[0] * rq * ga.x; xo = fv[1] * rq * ga.y;
      O.u[0] = f2bf(xe * c0.x - xo * c0.y); O.u[1] = f2bf(xe * c0.y + xo * c0.x);
      xe = fv[2] * rq * ga.z; xo = fv[3] * rq * ga.w;
      O.u[2] = f2bf(xe * c0.z - xo * c0.w); O.u[3] = f2bf(xe * c0.w + xo * c0.z);
      xe = fv[4] * rq * gb.x; xo = fv[5] * rq * gb.y;
      O.u[4] = f2bf(xe * c1.x - xo * c1.y); O.u[5] = f2bf(xe * c1.y + xo * c1.x);
      xe = fv[6] * rq * gb.z; xo = fv[7] * rq * gb.w;
      O.u[6] = f2bf(xe * c1.z - xo * c1.w); O.u[7] = f2bf(xe * c1.w + xo * c1.z);
      bq[kk] = O.s;
    }
  }

  // ---- K: fused norm + rope, then swizzled ds_write_b128 into K_s ----
#pragma unroll
  for (int it = 0; it < 6; ++it) {
    int c = it * 256 + tid;
    int kr = c >> 3, g = c & 7;
    union { float4 f; ushort u[8]; } L;
    L.f = kreg[it];
    float f0 = bf2f(L.u[0]), f1 = bf2f(L.u[1]), f2 = bf2f(L.u[2]), f3 = bf2f(L.u[3]);
    float f4 = bf2f(L.u[4]), f5 = bf2f(L.u[5]), f6 = bf2f(L.u[6]), f7 = bf2f(L.u[7]);
    float ss = f0 * f0 + f1 * f1 + f2 * f2 + f3 * f3 +
               f4 * f4 + f5 * f5 + f6 * f6 + f7 * f7;
    ss += __shfl_xor(ss, 1);
    ss += __shfl_xor(ss, 2);
    ss += __shfl_xor(ss, 4);
    const float rn = rsqrtf(ss * (1.f / 64.f) + 1e-6f);
    const float4 ga = *(const float4*)(kg + g * 8);
    const float4 gb = *(const float4*)(kg + g * 8 + 4);
    const float* cbp = csn + (size_t)mi6[it] * 64 + g * 8;
    const float4 c0 = *(const float4*)cbp;
    const float4 c1 = *(const float4*)(cbp + 4);
    union { short8 s; ushort u[8]; } O;
    float xe, xo;
    xe = f0 * rn * ga.x; xo = f1 * rn * ga.y;
    O.u[0] = f2bf(xe * c0.x - xo * c0.y); O.u[1] = f2bf(xe * c0.y + xo * c0.x);
    xe = f2 * rn * ga.z; xo = f3 * rn * ga.w;
    O.u[2] = f2bf(xe * c0.z - xo * c0.w); O.u[3] = f2bf(xe * c0.w + xo * c0.z);
    xe = f4 * rn * gb.x; xo = f5 * rn * gb.y;
    O.u[4] = f2bf(xe * c1.x - xo * c1.y); O.u[5] = f2bf(xe * c1.y + xo * c1.x);
    xe = f6 * rn * gb.z; xo = f7 * rn * gb.w;
    O.u[6] = f2bf(xe * c1.z - xo * c1.w); O.u[7] = f2bf(xe * c1.w + xo * c1.z);
    *(short8*)&K_s[kr * 64 + ((g ^ (kr & 7)) * 8)] = O.s;
  }

  __syncthreads();  // bar1: K staged (normed+roped)

  // ---- Vt transposed scatter-write (overlaps St on LDS pipe) ----
#pragma unroll
  for (int it = 0; it < 6; ++it) {
    int c = it * 256 + tid;
    int kr = c >> 3, gv = c & 7;
    int ck = kr >> 3, kin = kr & 7;
    union { float4 f; ushort u[8]; } vv;
    vv.f = vreg[it];
#pragma unroll
    for (int j = 0; j < 8; ++j) {
      int d = gv * 8 + j;
      int cks = ck ^ ((j ^ gv) & 7);       // group-preserving low-3 XOR
      Vt_s[d * 192 + cks * 8 + kin] = vv.u[j];
    }
  }

  // ---- St = K·Q^T : wave computes ONLY its 16 q (no redundancy) ----
  f32x4 st[12];
#pragma unroll
  for (int kf = 0; kf < 12; ++kf) st[kf] = (f32x4){0.f, 0.f, 0.f, 0.f};
#pragma unroll
  for (int kk = 0; kk < 2; ++kk)
#pragma unroll
    for (int kf = 0; kf < 12; ++kf) {
      int kr = kf * 16 + lm;
      short8 a = *(const short8*)&K_s[kr * 64 + (((kk * 4 + g4) ^ (kr & 7)) * 8)];
      st[kf] = __builtin_amdgcn_mfma_f32_16x16x32_bf16(a, bq[kk], st[kf], 0, 0, 0);
    }

  // ---- mask + softmax (lane: q-col = wave*16+lm; k = kf*16 + g4*4 + r) ----
  const int p = lm & 7;                   // (wave*16+lm)&7 == lm&7
  const int qh = hb + (p >> 2), qw = wb + (p & 3);
  const int loh = min(max(qh - 1, 0), 29), low = min(max(qw - 1, 0), 29);
  uint mk = 0;
#pragma unroll
  for (int kf = 0; kf < 12; ++kf) {
    int sc = kf * 2 + (g4 >> 1);
    int kh = sc / 6, kw = sc - kh * 6;
    int khg = hb0 + kh, kwg = wb0 + kw;   // nominal (unclamped) position
    bool ok = (khg >= loh) && (khg <= loh + 2) && (kwg >= low) && (kwg <= low + 2);
    mk |= (uint)ok << kf;
  }
  const float scale = 0.125f;
#pragma unroll
  for (int kf = 0; kf < 12; ++kf) {
    bool ok = (mk >> kf) & 1;
#pragma unroll
    for (int r = 0; r < 4; ++r)
      st[kf][r] = ok ? st[kf][r] * scale : -1e30f;
  }
  float mx = -1e30f;
#pragma unroll
  for (int kf = 0; kf < 12; ++kf)
#pragma unroll
    for (int r = 0; r < 4; ++r) mx = fmaxf(mx, st[kf][r]);
  mx = fmaxf(mx, __shfl_xor(mx, 16));
  mx = fmaxf(mx, __shfl_xor(mx, 32));
  float s = 0.f;
#pragma unroll
  for (int kf = 0; kf < 12; ++kf)
#pragma unroll
    for (int r = 0; r < 4; ++r) {
      float e = __expf(st[kf][r] - mx);
      st[kf][r] = e;
      s += e;
    }
  s += __shfl_xor(s, 16);
  s += __shfl_xor(s, 32);
  const float inv = 1.f / s;
  __syncthreads();  // bar2: K reads done (P may overwrite), Vt writes visible

  // ---- P write: wave-disjoint rows q = wave*16+lm; compile-time st idx ----
  {
    const int q = wave * 16 + lm;
    ushort* Prow = P_s + q * 192 + (g4 & 1) * 4;
#pragma unroll
    for (int kf = 0; kf < 12; ++kf) {
      uint lo = (uint)f2bf(st[kf][0] * inv) | ((uint)f2bf(st[kf][1] * inv) << 16);
      uint hi = (uint)f2bf(st[kf][2] * inv) | ((uint)f2bf(st[kf][3] * inv) << 16);
      int ck = kf * 2 + (g4 >> 1);
      int cks = ck ^ (lm & 7);            // group-preserving (q&7 == lm&7)
      uint2 val; val.x = lo; val.y = hi;
      *(uint2*)(Prow + cks * 8) = val;
    }
  }
  __syncthreads();  // bar3: P ready

  // ---- PV: wave owns d-block wave*16; out[q][d] for all 4 q-frags ----
  f32x4 ao0 = (f32x4){0.f, 0.f, 0.f, 0.f};
  f32x4 ao1 = (f32x4){0.f, 0.f, 0.f, 0.f};
  f32x4 ao2 = (f32x4){0.f, 0.f, 0.f, 0.f};
  f32x4 ao3 = (f32x4){0.f, 0.f, 0.f, 0.f};
  const int drow = wave * 16 + lm;
  const int dsw = (lm & 7) ^ ((wave * 2 + (lm >> 3)) & 7);
#pragma unroll
  for (int kk = 0; kk < 6; ++kk) {
    int ch = kk * 4 + g4;
    short8 bv = *(const short8*)&Vt_s[drow * 192 + ((ch ^ dsw) * 8)];
    int pch = (ch ^ (lm & 7)) * 8;
    short8 av0 = *(const short8*)&P_s[(0 * 16 + lm) * 192 + pch];
    short8 av1 = *(const short8*)&P_s[(1 * 16 + lm) * 192 + pch];
    short8 av2 = *(const short8*)&P_s[(2 * 16 + lm) * 192 + pch];
    short8 av3 = *(const short8*)&P_s[(3 * 16 + lm) * 192 + pch];
    ao0 = __builtin_amdgcn_mfma_f32_16x16x32_bf16(av0, bv, ao0, 0, 0, 0);
    ao1 = __builtin_amdgcn_mfma_f32_16x16x32_bf16(av1, bv, ao1, 0, 0, 0);
    ao2 = __builtin_amdgcn_mfma_f32_16x16x32_bf16(av2, bv, ao2, 0, 0, 0);
    ao3 = __builtin_amdgcn_mfma_f32_16x16x32_bf16(av3, bv, ao3, 0, 0, 0);
  }
  __syncthreads();  // bar4: PV's Vt/P reads done; O may overwrite Vt region

  // ---- epilogue: O via LDS (stride 68), coalesced bf16 store ----
#pragma unroll
  for (int r = 0; r < 4; ++r) {
    O_s[(0 * 16 + g4 * 4 + r) * 68 + (wave * 16 + lm)] = f2bf(ao0[r]);
    O_s[(1 * 16 + g4 * 4 + r) * 68 + (wave * 16 + lm)] = f2bf(ao1[r]);
    O_s[(2 * 16 + g4 * 4 + r) * 68 + (wave * 16 + lm)] = f2bf(ao2[r]);
    O_s[(3 * 16 + g4 * 4 + r) * 68 + (wave * 16 + lm)] = f2bf(ao3[r]);
  }
  __syncthreads();  // bar5
#pragma unroll
  for (int i = 0; i < 2; ++i) {
    int idx = i * 256 + tid;
    int q = idx >> 3, c = idx & 7;
    short8 v = *(const short8*)&O_s[q * 68 + c * 8];
    int tq = q >> 3, pp = q & 7;
    size_t m = (((size_t)(b * 8 + tq) * 32 + (hb + (pp >> 2))) * 32 + (wb + (pp & 3)));
    *(short8*)(outb + m * (size_t)C_ + n * 64 + c * 8) = v;
  }
}

// ---------------------------------------------------------------------------
extern "C" void kernel_launch(void* const* d_in, const int* in_sizes, int n_in,
                              void* d_out, int out_size, void* d_ws, size_t ws_size,
                              hipStream_t stream) {
  const float* x     = (const float*)d_in[0];
  const float* freqs = (const float*)d_in[1];
  const float* w_in  = (const float*)d_in[2];
  const float* w_out = (const float*)d_in[3];
  const float* qg    = (const float*)d_in[4];
  const float* kg    = (const float*)d_in[5];
  float* out = (float*)d_out;

  char* ws = (char*)d_ws;
  ushort* qkv   = (ushort*)ws;                                    // 50.3 MB bf16
  ushort* xb    = (ushort*)(ws + (size_t)NTOK * C3 * 2);          // 16.8 MB
  ushort* wib   = xb + (size_t)NTOK * C_;                         // 1.5 MB
  ushort* wob   = wib + (size_t)C3 * C_;                          // 0.5 MB
  ushort* attnb = wob + (size_t)C_ * C_;                          // 16.8 MB
  // cos/sin table lives in d_out scratch (2 MB): written by cast3, read by
  // attn, then fully overwritten by gemm2's fp32 output. Stream-ordered.
  float* csn = out;

  // 0) fused casts + sincos table (128 extra blocks)
  cast3_kernel<<<4736, 256, 0, stream>>>(x, w_in, w_out, freqs, xb, wib, wob,
                                         (float2*)csn);

  // 1) qkv = x @ w_in^T (bf16 out, RAW — norm/rope fused into attn).
  //    grid 1536 = 128 bm x 12 bn, XCD-chunked.
  gemm_bt_bf16<true><<<1536, 256, 0, stream>>>(xb, wib, qkv, C3, C_, 12);
  // 2) MFMA neighborhood attention with fused RMSNorm+RoPE -> attnb.
  //    grid 2048 = 2b x 8n x 16th x 8tw.
  attn_kernel<<<2048, 256, 0, stream>>>(qkv, attnb, csn, qg, kg);
  // 3) out = attn @ w_out^T (fp32 out). grid 512 = 128 bm x 4 bn.
  gemm_bt_bf16<false><<<512, 256, 0, stream>>>(attnb, wob, out, C_, C_, 4);
}

// Round 5
// 99.646 us; speedup vs baseline: 1.3287x; 1.0122x over previous
//
#include <hip/hip_runtime.h>
#include <hip/hip_bf16.h>
#include <math.h>

#define NH 8
#define C_ 512
#define C3 1536
#define NTOK 16384   // b*t*h*w = 2*8*32*32

typedef __attribute__((ext_vector_type(8))) short short8;
typedef __attribute__((ext_vector_type(4))) float f32x4;
typedef __attribute__((address_space(3))) void* lds_ptr_t;
typedef const __attribute__((address_space(1))) void* gbl_ptr_t;

static __device__ __forceinline__ ushort f2bf(float f) {
  __hip_bfloat16 h = __float2bfloat16(f);
  return *reinterpret_cast<ushort*>(&h);
}
static __device__ __forceinline__ float bf2f(ushort u) {
  uint t = ((uint)u) << 16;
  float f;
  __builtin_memcpy(&f, &t, 4);
  return f;
}

// ---------------------------------------------------------------------------
// K0: fused fp32 -> bf16 cast for x, w_in, w_out PLUS cos/sin table for rope.
// csn[idx] = (cosf(freqs[idx]), sinf(freqs[idx])), idx over 8*32*32*32 = 262144.
// Table lives in d_out scratch (overwritten later by gemm2; stream-ordered).
// ---------------------------------------------------------------------------
__global__ __launch_bounds__(256) void cast3_kernel(
    const float* __restrict__ x, const float* __restrict__ wi,
    const float* __restrict__ wo, const float* __restrict__ fr,
    ushort* __restrict__ xb, ushort* __restrict__ wib,
    ushort* __restrict__ wob, float2* __restrict__ csn) {
  const int blk = blockIdx.x;
  if (blk >= 4608) {   // 128 blocks: sincos table (8 entries/thread)
    int i = (blk - 4608) * 256 + threadIdx.x;
    const float4* fp = (const float4*)fr + (size_t)i * 2;
    float4 a = fp[0], b = fp[1];
    float v[8] = {a.x, a.y, a.z, a.w, b.x, b.y, b.z, b.w};
    float2 o[8];
#pragma unroll
    for (int j = 0; j < 8; ++j) { o[j].x = cosf(v[j]); o[j].y = sinf(v[j]); }
    float4* op = (float4*)(csn + (size_t)i * 8);
    op[0] = make_float4(o[0].x, o[0].y, o[1].x, o[1].y);
    op[1] = make_float4(o[2].x, o[2].y, o[3].x, o[3].y);
    op[2] = make_float4(o[4].x, o[4].y, o[5].x, o[5].y);
    op[3] = make_float4(o[6].x, o[6].y, o[7].x, o[7].y);
    return;
  }
  const float* src;
  ushort* dst;
  int i;
  if (blk < 4096)      { src = x;  dst = xb;  i = blk * 256 + threadIdx.x; }
  else if (blk < 4480) { src = wi; dst = wib; i = (blk - 4096) * 256 + threadIdx.x; }
  else                 { src = wo; dst = wob; i = (blk - 4480) * 256 + threadIdx.x; }
  const float4* p = (const float4*)src + (size_t)i * 2;
  float4 v0 = p[0], v1 = p[1];
  union { ushort u[8]; uint4 v; } r;
  r.u[0] = f2bf(v0.x); r.u[1] = f2bf(v0.y); r.u[2] = f2bf(v0.z); r.u[3] = f2bf(v0.w);
  r.u[4] = f2bf(v1.x); r.u[5] = f2bf(v1.y); r.u[6] = f2bf(v1.z); r.u[7] = f2bf(v1.w);
  *(uint4*)(dst + (size_t)i * 8) = r.v;
}

// ---------------------------------------------------------------------------
// bf16 NT GEMM via MFMA: 128x128x32 tile, NOW with 3-buffer LDS / 2-deep
// prefetch and counted vmcnt (T4): the old 2-buffer __syncthreads drained
// vmcnt(0) every K-step, exposing ~(latency - 1 iter) of stall per barrier.
// Steady state: issue stage(t+2), compute buf[t%3], wait vmcnt(4) (drains
// stage(t+1), leaves stage(t+2) in flight), raw s_barrier + compiler fence.
// Tail: t=nt-2 waits vmcnt(0); t=nt-1 no barrier (epilogue syncthreads).
// LDS 48 KB -> still 3 blocks/CU. T2 source swizzle + T1 XCD swizzle kept.
// ---------------------------------------------------------------------------
#define TBM 128
#define TBN 128
#define TBK 32
#define TILE_U ((TBM + TBN) * TBK)

static __device__ __forceinline__ void stage_tile(
    const ushort* __restrict__ A, const ushort* __restrict__ B,
    ushort* As, ushort* Bs, int bm, int bn, int K, int k0, int tid) {
#pragma unroll
  for (int it = 0; it < 2; ++it) {
    int c = it * 256 + tid;
    int row = c >> 2;
    int sk = ((c & 3) ^ ((row >> 1) & 3)) * 8;
    __builtin_amdgcn_global_load_lds(
        (gbl_ptr_t)(const void*)(A + (size_t)(bm + row) * K + k0 + sk),
        (lds_ptr_t)(As + (size_t)c * 8), 16, 0, 0);
    __builtin_amdgcn_global_load_lds(
        (gbl_ptr_t)(const void*)(B + (size_t)(bn + row) * K + k0 + sk),
        (lds_ptr_t)(Bs + (size_t)c * 8), 16, 0, 0);
  }
}

template <bool BF16OUT>
__global__ __launch_bounds__(256) void gemm_bt_bf16(
    const ushort* __restrict__ A, const ushort* __restrict__ B,
    void* __restrict__ Cv, int N, int K, int GX) {
  __shared__ ushort smem[3 * TILE_U];   // 48 KB
  const int tid  = threadIdx.x;
  const int wave = tid >> 6;
  const int lane = tid & 63;
  const int nwg = gridDim.x;
  const int wg = (blockIdx.x & 7) * (nwg >> 3) + (blockIdx.x >> 3);
  const int bm = (wg / GX) * TBM;
  const int bn = (wg % GX) * TBN;
  const int wr = (wave >> 1) * 64;
  const int wc = (wave & 1) * 64;
  const int lm = lane & 15;
  const int g4 = lane >> 4;

  f32x4 acc[4][4];
#pragma unroll
  for (int m = 0; m < 4; ++m)
#pragma unroll
    for (int n = 0; n < 4; ++n) acc[m][n] = (f32x4){0.f, 0.f, 0.f, 0.f};

  const int ko = (g4 ^ ((lm >> 1) & 3)) * 8;

  const int nt = K / TBK;   // 16
  // prologue: 2-deep prefetch (tiles 0,1 -> buf 0,1); wait tile0 only.
  stage_tile(A, B, smem, smem + TBM * TBK, bm, bn, K, 0, tid);
  {
    ushort* b1 = smem + TILE_U;
    stage_tile(A, B, b1, b1 + TBM * TBK, bm, bn, K, TBK, tid);
  }
  asm volatile("s_waitcnt vmcnt(4)" ::: "memory");
  __builtin_amdgcn_s_barrier();
  asm volatile("" ::: "memory");

  for (int t = 0; t < nt; ++t) {
    if (t + 2 < nt) {
      ushort* bn3 = smem + ((t + 2) % 3) * TILE_U;
      stage_tile(A, B, bn3, bn3 + TBM * TBK, bm, bn, K, (t + 2) * TBK, tid);
    }
    const ushort* As = smem + (t % 3) * TILE_U;
    const ushort* Bs = As + TBM * TBK;
    short8 av[4], bv[4];
#pragma unroll
    for (int m = 0; m < 4; ++m)
      av[m] = *(const short8*)&As[(wr + m * 16 + lm) * TBK + ko];
#pragma unroll
    for (int n = 0; n < 4; ++n)
      bv[n] = *(const short8*)&Bs[(wc + n * 16 + lm) * TBK + ko];
#pragma unroll
    for (int m = 0; m < 4; ++m)
#pragma unroll
      for (int n = 0; n < 4; ++n)
        acc[m][n] = __builtin_amdgcn_mfma_f32_16x16x32_bf16(av[m], bv[n], acc[m][n], 0, 0, 0);
    if (t + 1 < nt) {
      if (t + 2 < nt) asm volatile("s_waitcnt vmcnt(4)" ::: "memory");
      else            asm volatile("s_waitcnt vmcnt(0)" ::: "memory");
      __builtin_amdgcn_s_barrier();
      asm volatile("" ::: "memory");
    }
  }
  __syncthreads();   // all waves done computing; LDS reusable for epilogue

  const int cr = g4 * 4;
  const int cc = lm;

  if (BF16OUT) {
    ushort* Cs = smem;
    ushort* C = (ushort*)Cv;
#pragma unroll
    for (int h = 0; h < 2; ++h) {
      __syncthreads();
      if ((wave >> 1) == h) {
#pragma unroll
        for (int m = 0; m < 4; ++m)
#pragma unroll
          for (int n = 0; n < 4; ++n)
#pragma unroll
            for (int r = 0; r < 4; ++r)
              Cs[(m * 16 + cr + r) * 128 + wc + n * 16 + cc] = f2bf(acc[m][n][r]);
      }
      __syncthreads();
#pragma unroll
      for (int i = 0; i < 4; ++i) {
        int idx = i * 256 + tid;
        int row = idx >> 4, ch = idx & 15;
        uint4 v = *(const uint4*)&Cs[row * 128 + ch * 8];
        *(uint4*)(C + (size_t)(bm + h * 64 + row) * N + bn + ch * 8) = v;
      }
    }
  } else {
    float* Csf = (float*)smem;
    float* C = (float*)Cv;
#pragma unroll
    for (int s = 0; s < 4; ++s) {
      __syncthreads();
      if ((wave >> 1) == (s >> 1)) {
#pragma unroll
        for (int mi = 0; mi < 2; ++mi)
#pragma unroll
          for (int n = 0; n < 4; ++n)
#pragma unroll
            for (int r = 0; r < 4; ++r) {
              int m = (s & 1) * 2 + mi;
              Csf[(mi * 16 + cr + r) * 128 + wc + n * 16 + cc] = acc[m][n][r];
            }
      }
      __syncthreads();
#pragma unroll
      for (int i = 0; i < 4; ++i) {
        int idx = i * 256 + tid;
        int row = idx >> 5, ch = idx & 31;
        float4 v = *(const float4*)&Csf[row * 128 + ch * 4];
        *(float4*)(C + (size_t)(bm + s * 32 + row) * N + bn + ch * 4) = v;
      }
    }
  }
}

// ---------------------------------------------------------------------------
// K3: MFMA neighborhood attention with FUSED RMSNorm + RoPE on q and k.
// (unchanged from R4)
// ---------------------------------------------------------------------------
__global__ __launch_bounds__(256) void attn_kernel(
    const ushort* __restrict__ qkv, ushort* __restrict__ outb,
    const float* __restrict__ csn, const float* __restrict__ qg,
    const float* __restrict__ kg) {
  __shared__ ushort lds[24576];          // 48 KB
  ushort* K_s  = lds;                    // [192 k][64 d], chunk swz c^(kr&7)
  ushort* Vt_s = lds + 12288;            // [64 d][192 k], chunk low3 ^ (d&7)^((d>>3)&7)
  ushort* P_s  = lds;                    // [64 q][192 k], chunk low3 ^ (q&7)
  ushort* O_s  = lds + 12288;            // [64 q][68 d-stride]

  const int tid = threadIdx.x;
  const int wave = tid >> 6;
  const int lane = tid & 63;
  const int lin = blockIdx.x;
  const int bid = (lin & 7) * 256 + (lin >> 3);   // XCD-chunked (2048 % 8 == 0)
  // bid = ((b*8 + n)*16 + th)*8 + tw
  const int tw = bid & 7, th = (bid >> 3) & 15, n = (bid >> 7) & 7, b = bid >> 10;
  const int hb = th * 2, wb = tw * 4;
  const int hb0 = max(hb - 1, 0), wb0 = max(wb - 1, 0);
  const int lm = lane & 15, g4 = lane >> 4;

  // ---- V + K: reg-stage 6 chunks/thread each ----
  float4 vreg[6], kreg[6];
  int mi6[6];
#pragma unroll
  for (int it = 0; it < 6; ++it) {
    int c = it * 256 + tid;
    int kr = c >> 3, gv = c & 7;
    int sc = kr >> 3, t = kr & 7;
    int kh = sc / 6, kw = sc - kh * 6;
    int hh = min(hb0 + kh, 31), ww = min(wb0 + kw, 31);
    size_t m = (((size_t)(b * 8 + t) * 32 + hh) * 32 + ww);
    mi6[it] = (int)(m & 8191);
    const ushort* bp = qkv + m * C3 + n * 192;
    vreg[it] = *(const float4*)(bp + 128 + gv * 8);
    kreg[it] = *(const float4*)(bp + 64 + gv * 8);
  }

  // ---- Q: wave's 16-q fragment, fused norm + rope in-register ----
  short8 bq[2];
  {
    int q = wave * 16 + lm;
    int tq = q >> 3, p = q & 7;
    size_t mq = (((size_t)(b * 8 + tq) * 32 + (hb + (p >> 2))) * 32 + (wb + (p & 3)));
    const ushort* qp = qkv + mq * C3 + n * 192;
    union { short8 s; ushort u[8]; } Lq0, Lq1;
    Lq0.s = *(const short8*)(qp + g4 * 8);
    Lq1.s = *(const short8*)(qp + (4 + g4) * 8);
    float fq[16];
    float ssq = 0.f;
#pragma unroll
    for (int j = 0; j < 8; ++j) { fq[j] = bf2f(Lq0.u[j]); ssq += fq[j] * fq[j]; }
#pragma unroll
    for (int j = 0; j < 8; ++j) { fq[8 + j] = bf2f(Lq1.u[j]); ssq += fq[8 + j] * fq[8 + j]; }
    ssq += __shfl_xor(ssq, 16);
    ssq += __shfl_xor(ssq, 32);
    const float rq = rsqrtf(ssq * (1.f / 64.f) + 1e-6f);
    const int miq = (int)(mq & 8191);
#pragma unroll
    for (int kk = 0; kk < 2; ++kk) {
      const int ch0 = (kk * 4 + g4) * 8;
      const float4 ga = *(const float4*)(qg + ch0);
      const float4 gb = *(const float4*)(qg + ch0 + 4);
      const float* cbp = csn + (size_t)miq * 64 + ch0;
      const float4 c0 = *(const float4*)cbp;
      const float4 c1 = *(const float4*)(cbp + 4);
      const float* fv = &fq[kk * 8];
      union { short8 s; ushort u[8]; } O;
      float xe, xo;
      xe = fv[0] * rq * ga.x; xo = fv[1] * rq * ga.y;
      O.u[0] = f2bf(xe * c0.x - xo * c0.y); O.u[1] = f2bf(xe * c0.y + xo * c0.x);
      xe = fv[2] * rq * ga.z; xo = fv[3] * rq * ga.w;
      O.u[2] = f2bf(xe * c0.z - xo * c0.w); O.u[3] = f2bf(xe * c0.w + xo * c0.z);
      xe = fv[4] * rq * gb.x; xo = fv[5] * rq * gb.y;
      O.u[4] = f2bf(xe * c1.x - xo * c1.y); O.u[5] = f2bf(xe * c1.y + xo * c1.x);
      xe = fv[6] * rq * gb.z; xo = fv[7] * rq * gb.w;
      O.u[6] = f2bf(xe * c1.z - xo * c1.w); O.u[7] = f2bf(xe * c1.w + xo * c1.z);
      bq[kk] = O.s;
    }
  }

  // ---- K: fused norm + rope, then swizzled ds_write_b128 into K_s ----
#pragma unroll
  for (int it = 0; it < 6; ++it) {
    int c = it * 256 + tid;
    int kr = c >> 3, g = c & 7;
    union { float4 f; ushort u[8]; } L;
    L.f = kreg[it];
    float f0 = bf2f(L.u[0]), f1 = bf2f(L.u[1]), f2 = bf2f(L.u[2]), f3 = bf2f(L.u[3]);
    float f4 = bf2f(L.u[4]), f5 = bf2f(L.u[5]), f6 = bf2f(L.u[6]), f7 = bf2f(L.u[7]);
    float ss = f0 * f0 + f1 * f1 + f2 * f2 + f3 * f3 +
               f4 * f4 + f5 * f5 + f6 * f6 + f7 * f7;
    ss += __shfl_xor(ss, 1);
    ss += __shfl_xor(ss, 2);
    ss += __shfl_xor(ss, 4);
    const float rn = rsqrtf(ss * (1.f / 64.f) + 1e-6f);
    const float4 ga = *(const float4*)(kg + g * 8);
    const float4 gb = *(const float4*)(kg + g * 8 + 4);
    const float* cbp = csn + (size_t)mi6[it] * 64 + g * 8;
    const float4 c0 = *(const float4*)cbp;
    const float4 c1 = *(const float4*)(cbp + 4);
    union { short8 s; ushort u[8]; } O;
    float xe, xo;
    xe = f0 * rn * ga.x; xo = f1 * rn * ga.y;
    O.u[0] = f2bf(xe * c0.x - xo * c0.y); O.u[1] = f2bf(xe * c0.y + xo * c0.x);
    xe = f2 * rn * ga.z; xo = f3 * rn * ga.w;
    O.u[2] = f2bf(xe * c0.z - xo * c0.w); O.u[3] = f2bf(xe * c0.w + xo * c0.z);
    xe = f4 * rn * gb.x; xo = f5 * rn * gb.y;
    O.u[4] = f2bf(xe * c1.x - xo * c1.y); O.u[5] = f2bf(xe * c1.y + xo * c1.x);
    xe = f6 * rn * gb.z; xo = f7 * rn * gb.w;
    O.u[6] = f2bf(xe * c1.z - xo * c1.w); O.u[7] = f2bf(xe * c1.w + xo * c1.z);
    *(short8*)&K_s[kr * 64 + ((g ^ (kr & 7)) * 8)] = O.s;
  }

  __syncthreads();  // bar1: K staged (normed+roped)

  // ---- Vt transposed scatter-write (overlaps St on LDS pipe) ----
#pragma unroll
  for (int it = 0; it < 6; ++it) {
    int c = it * 256 + tid;
    int kr = c >> 3, gv = c & 7;
    int ck = kr >> 3, kin = kr & 7;
    union { float4 f; ushort u[8]; } vv;
    vv.f = vreg[it];
#pragma unroll
    for (int j = 0; j < 8; ++j) {
      int d = gv * 8 + j;
      int cks = ck ^ ((j ^ gv) & 7);       // group-preserving low-3 XOR
      Vt_s[d * 192 + cks * 8 + kin] = vv.u[j];
    }
  }

  // ---- St = K·Q^T : wave computes ONLY its 16 q (no redundancy) ----
  f32x4 st[12];
#pragma unroll
  for (int kf = 0; kf < 12; ++kf) st[kf] = (f32x4){0.f, 0.f, 0.f, 0.f};
#pragma unroll
  for (int kk = 0; kk < 2; ++kk)
#pragma unroll
    for (int kf = 0; kf < 12; ++kf) {
      int kr = kf * 16 + lm;
      short8 a = *(const short8*)&K_s[kr * 64 + (((kk * 4 + g4) ^ (kr & 7)) * 8)];
      st[kf] = __builtin_amdgcn_mfma_f32_16x16x32_bf16(a, bq[kk], st[kf], 0, 0, 0);
    }

  // ---- mask + softmax (lane: q-col = wave*16+lm; k = kf*16 + g4*4 + r) ----
  const int p = lm & 7;                   // (wave*16+lm)&7 == lm&7
  const int qh = hb + (p >> 2), qw = wb + (p & 3);
  const int loh = min(max(qh - 1, 0), 29), low = min(max(qw - 1, 0), 29);
  uint mk = 0;
#pragma unroll
  for (int kf = 0; kf < 12; ++kf) {
    int sc = kf * 2 + (g4 >> 1);
    int kh = sc / 6, kw = sc - kh * 6;
    int khg = hb0 + kh, kwg = wb0 + kw;   // nominal (unclamped) position
    bool ok = (khg >= loh) && (khg <= loh + 2) && (kwg >= low) && (kwg <= low + 2);
    mk |= (uint)ok << kf;
  }
  const float scale = 0.125f;
#pragma unroll
  for (int kf = 0; kf < 12; ++kf) {
    bool ok = (mk >> kf) & 1;
#pragma unroll
    for (int r = 0; r < 4; ++r)
      st[kf][r] = ok ? st[kf][r] * scale : -1e30f;
  }
  float mx = -1e30f;
#pragma unroll
  for (int kf = 0; kf < 12; ++kf)
#pragma unroll
    for (int r = 0; r < 4; ++r) mx = fmaxf(mx, st[kf][r]);
  mx = fmaxf(mx, __shfl_xor(mx, 16));
  mx = fmaxf(mx, __shfl_xor(mx, 32));
  float s = 0.f;
#pragma unroll
  for (int kf = 0; kf < 12; ++kf)
#pragma unroll
    for (int r = 0; r < 4; ++r) {
      float e = __expf(st[kf][r] - mx);
      st[kf][r] = e;
      s += e;
    }
  s += __shfl_xor(s, 16);
  s += __shfl_xor(s, 32);
  const float inv = 1.f / s;
  __syncthreads();  // bar2: K reads done (P may overwrite), Vt writes visible

  // ---- P write: wave-disjoint rows q = wave*16+lm; compile-time st idx ----
  {
    const int q = wave * 16 + lm;
    ushort* Prow = P_s + q * 192 + (g4 & 1) * 4;
#pragma unroll
    for (int kf = 0; kf < 12; ++kf) {
      uint lo = (uint)f2bf(st[kf][0] * inv) | ((uint)f2bf(st[kf][1] * inv) << 16);
      uint hi = (uint)f2bf(st[kf][2] * inv) | ((uint)f2bf(st[kf][3] * inv) << 16);
      int ck = kf * 2 + (g4 >> 1);
      int cks = ck ^ (lm & 7);            // group-preserving (q&7 == lm&7)
      uint2 val; val.x = lo; val.y = hi;
      *(uint2*)(Prow + cks * 8) = val;
    }
  }
  __syncthreads();  // bar3: P ready

  // ---- PV: wave owns d-block wave*16; out[q][d] for all 4 q-frags ----
  f32x4 ao0 = (f32x4){0.f, 0.f, 0.f, 0.f};
  f32x4 ao1 = (f32x4){0.f, 0.f, 0.f, 0.f};
  f32x4 ao2 = (f32x4){0.f, 0.f, 0.f, 0.f};
  f32x4 ao3 = (f32x4){0.f, 0.f, 0.f, 0.f};
  const int drow = wave * 16 + lm;
  const int dsw = (lm & 7) ^ ((wave * 2 + (lm >> 3)) & 7);
#pragma unroll
  for (int kk = 0; kk < 6; ++kk) {
    int ch = kk * 4 + g4;
    short8 bv = *(const short8*)&Vt_s[drow * 192 + ((ch ^ dsw) * 8)];
    int pch = (ch ^ (lm & 7)) * 8;
    short8 av0 = *(const short8*)&P_s[(0 * 16 + lm) * 192 + pch];
    short8 av1 = *(const short8*)&P_s[(1 * 16 + lm) * 192 + pch];
    short8 av2 = *(const short8*)&P_s[(2 * 16 + lm) * 192 + pch];
    short8 av3 = *(const short8*)&P_s[(3 * 16 + lm) * 192 + pch];
    ao0 = __builtin_amdgcn_mfma_f32_16x16x32_bf16(av0, bv, ao0, 0, 0, 0);
    ao1 = __builtin_amdgcn_mfma_f32_16x16x32_bf16(av1, bv, ao1, 0, 0, 0);
    ao2 = __builtin_amdgcn_mfma_f32_16x16x32_bf16(av2, bv, ao2, 0, 0, 0);
    ao3 = __builtin_amdgcn_mfma_f32_16x16x32_bf16(av3, bv, ao3, 0, 0, 0);
  }
  __syncthreads();  // bar4: PV's Vt/P reads done; O may overwrite Vt region

  // ---- epilogue: O via LDS (stride 68), coalesced bf16 store ----
#pragma unroll
  for (int r = 0; r < 4; ++r) {
    O_s[(0 * 16 + g4 * 4 + r) * 68 + (wave * 16 + lm)] = f2bf(ao0[r]);
    O_s[(1 * 16 + g4 * 4 + r) * 68 + (wave * 16 + lm)] = f2bf(ao1[r]);
    O_s[(2 * 16 + g4 * 4 + r) * 68 + (wave * 16 + lm)] = f2bf(ao2[r]);
    O_s[(3 * 16 + g4 * 4 + r) * 68 + (wave * 16 + lm)] = f2bf(ao3[r]);
  }
  __syncthreads();  // bar5
#pragma unroll
  for (int i = 0; i < 2; ++i) {
    int idx = i * 256 + tid;
    int q = idx >> 3, c = idx & 7;
    short8 v = *(const short8*)&O_s[q * 68 + c * 8];
    int tq = q >> 3, pp = q & 7;
    size_t m = (((size_t)(b * 8 + tq) * 32 + (hb + (pp >> 2))) * 32 + (wb + (pp & 3)));
    *(short8*)(outb + m * (size_t)C_ + n * 64 + c * 8) = v;
  }
}

// ---------------------------------------------------------------------------
extern "C" void kernel_launch(void* const* d_in, const int* in_sizes, int n_in,
                              void* d_out, int out_size, void* d_ws, size_t ws_size,
                              hipStream_t stream) {
  const float* x     = (const float*)d_in[0];
  const float* freqs = (const float*)d_in[1];
  const float* w_in  = (const float*)d_in[2];
  const float* w_out = (const float*)d_in[3];
  const float* qg    = (const float*)d_in[4];
  const float* kg    = (const float*)d_in[5];
  float* out = (float*)d_out;

  char* ws = (char*)d_ws;
  ushort* qkv   = (ushort*)ws;                                    // 50.3 MB bf16
  ushort* xb    = (ushort*)(ws + (size_t)NTOK * C3 * 2);          // 16.8 MB
  ushort* wib   = xb + (size_t)NTOK * C_;                         // 1.5 MB
  ushort* wob   = wib + (size_t)C3 * C_;                          // 0.5 MB
  ushort* attnb = wob + (size_t)C_ * C_;                          // 16.8 MB
  // cos/sin table lives in d_out scratch (2 MB): written by cast3, read by
  // attn, then fully overwritten by gemm2's fp32 output. Stream-ordered.
  float* csn = out;

  // 0) fused casts + sincos table (128 extra blocks)
  cast3_kernel<<<4736, 256, 0, stream>>>(x, w_in, w_out, freqs, xb, wib, wob,
                                         (float2*)csn);

  // 1) qkv = x @ w_in^T (bf16 out, RAW — norm/rope fused into attn).
  //    grid 1536 = 128 bm x 12 bn, XCD-chunked.
  gemm_bt_bf16<true><<<1536, 256, 0, stream>>>(xb, wib, qkv, C3, C_, 12);
  // 2) MFMA neighborhood attention with fused RMSNorm+RoPE -> attnb.
  //    grid 2048 = 2b x 8n x 16th x 8tw.
  attn_kernel<<<2048, 256, 0, stream>>>(qkv, attnb, csn, qg, kg);
  // 3) out = attn @ w_out^T (fp32 out). grid 512 = 128 bm x 4 bn.
  gemm_bt_bf16<false><<<512, 256, 0, stream>>>(attnb, wob, out, C_, C_, 4);
}